// Round 1
// baseline (595.773 us; speedup 1.0000x reference)
//
#include <hip/hip_runtime.h>
#include <hip/hip_bf16.h>

#define NN 50000      // nodes
#define NM 10000      // hyperedges
#define NE 500000     // incidences
#define DIN 128       // input feature dim
#define DOUT 64       // per-head out dim
#define DH  128       // H*DOUT

// ---------------- workspace layout (floats) ----------------
// 0         vke / vagg     6,400,000
// 6,400,000 ex             1,000,000
// 7,400,000 eagg / ekv     1,280,000
// 8,680,000 hsum              20,000
// 8,700,000 nsum             100,000
// 8,800,000 el              100,000
// 8,900,000 er               20,000
// 8,920,000 el2              20,000
// 8,940,000 er2             100,000
// 9,040,000 cqe                 256
// 9,040,256 cqv                 256
static const size_t OFF_VKE  = 0;
static const size_t OFF_EX   = 6400000;
static const size_t OFF_EAGG = 7400000;
static const size_t OFF_HSUM = 8680000;
static const size_t OFF_NSUM = 8700000;
static const size_t OFF_EL   = 8800000;
static const size_t OFF_ER   = 8900000;
static const size_t OFF_EL2  = 8920000;
static const size_t OFF_ER2  = 8940000;
static const size_t OFF_CQE  = 9040000;
static const size_t OFF_CQV  = 9040256;

// ---- GEMM [R,128] @ [128,128] -> Y [R,128], plus el[r][h] = sum_d Y*attn ----
template<int RPB>
__global__ void gemm128_el_kernel(const float* __restrict__ X, const float* __restrict__ W,
                                  const float* __restrict__ attn, float* __restrict__ Y,
                                  float* __restrict__ el, int R) {
    __shared__ float rows[RPB][128];
    int tid = threadIdx.x;              // 0..127
    int r0 = blockIdx.x * RPB;
    for (int r = 0; r < RPB; ++r) {
        int m = r0 + r;
        rows[r][tid] = (m < R) ? X[(size_t)m * 128 + tid] : 0.f;
    }
    __syncthreads();
    float acc[RPB];
    #pragma unroll
    for (int r = 0; r < RPB; ++r) acc[r] = 0.f;
    #pragma unroll 8
    for (int k = 0; k < 128; ++k) {
        float wv = W[k * 128 + tid];
        #pragma unroll
        for (int r = 0; r < RPB; ++r) acc[r] += rows[r][k] * wv;
    }
    float av = attn[tid];
    int h = tid >> 6;
    for (int r = 0; r < RPB; ++r) {
        int m = r0 + r;
        if (m < R) Y[(size_t)m * 128 + tid] = acc[r];
        float v = acc[r] * av;
        for (int off = 32; off > 0; off >>= 1) v += __shfl_down(v, off);
        if ((tid & 63) == 0 && m < R) el[m * 2 + h] = v;
    }
}

// ---- GEMM [R,64] @ [64,128] -> Y [R,128], plus el reduce ----
template<int RPB>
__global__ void gemm64_el_kernel(const float* __restrict__ X, const float* __restrict__ W,
                                 const float* __restrict__ attn, float* __restrict__ Y,
                                 float* __restrict__ el, int R) {
    __shared__ float rows[RPB][64];
    int tid = threadIdx.x;              // 0..127
    int r0 = blockIdx.x * RPB;
    for (int i = tid; i < RPB * 64; i += 128) {
        int r = i >> 6, k = i & 63;
        int m = r0 + r;
        rows[r][k] = (m < R) ? X[(size_t)m * 64 + k] : 0.f;
    }
    __syncthreads();
    float acc[RPB];
    #pragma unroll
    for (int r = 0; r < RPB; ++r) acc[r] = 0.f;
    #pragma unroll 8
    for (int k = 0; k < 64; ++k) {
        float wv = W[k * 128 + tid];
        #pragma unroll
        for (int r = 0; r < RPB; ++r) acc[r] += rows[r][k] * wv;
    }
    float av = attn[tid];
    int h = tid >> 6;
    for (int r = 0; r < RPB; ++r) {
        int m = r0 + r;
        if (m < R) Y[(size_t)m * 128 + tid] = acc[r];
        float v = acc[r] * av;
        for (int off = 32; off > 0; off >>= 1) v += __shfl_down(v, off);
        if ((tid & 63) == 0 && m < R) el[m * 2 + h] = v;
    }
}

// ---- c[h*128+k] = sum_j W[k*128 + h*64 + j] * attn[h*64+j] (one block, 256 thr) ----
__global__ void fold_attn_kernel(const float* __restrict__ W, const float* __restrict__ attn,
                                 float* __restrict__ c) {
    int t = threadIdx.x;                 // 0..255
    int h = t >> 7, k = t & 127;
    float s = 0.f;
    #pragma unroll 8
    for (int j = 0; j < 64; ++j) s += W[k * 128 + h * 64 + j] * attn[h * 64 + j];
    c[h * 128 + k] = s;
}

// ---- er[m][h] = X[m,:] . c[h,:], one wave per row, 4 rows/block ----
__global__ void rows_dot_c_kernel(const float* __restrict__ X, const float* __restrict__ c,
                                  float* __restrict__ er, int R) {
    int tid = threadIdx.x;               // 0..255
    int wave = tid >> 6, lane = tid & 63;
    int m = blockIdx.x * 4 + wave;
    if (m >= R) return;
    float x0 = X[(size_t)m * 128 + lane];
    float x1 = X[(size_t)m * 128 + 64 + lane];
    float a0 = x0 * c[lane]       + x1 * c[64 + lane];
    float a1 = x0 * c[128 + lane] + x1 * c[192 + lane];
    for (int off = 32; off > 0; off >>= 1) {
        a0 += __shfl_down(a0, off);
        a1 += __shfl_down(a1, off);
    }
    if (lane == 0) { er[m * 2] = a0; er[m * 2 + 1] = a1; }
}

// ---- score -> exp -> atomic segment-sum (no max pass; scores are small) ----
__global__ void score_exp_sum_kernel(const int* __restrict__ seg_src, const int* __restrict__ seg_dst,
                                     const float* __restrict__ el_src, const float* __restrict__ er_dst,
                                     float* __restrict__ exbuf, float* __restrict__ segsum, int E) {
    int t = blockIdx.x * blockDim.x + threadIdx.x;
    if (t >= E * 2) return;
    int e = t >> 1, h = t & 1;
    int vs = seg_src[e], vd = seg_dst[e];
    float s = el_src[vs * 2 + h] + er_dst[vd * 2 + h];
    s = fmaxf(s, 0.f);
    float ex = __expf(s);
    exbuf[t] = ex;
    atomicAdd(&segsum[vd * 2 + h], ex);
}

// ---- msg scatter: agg[dst, j] += src[srcrow, j] * (ex / segsum[dst]) ----
__global__ void scatter_kernel(const int* __restrict__ srcidx, const int* __restrict__ dstidx,
                               const float* __restrict__ exbuf, const float* __restrict__ segsum,
                               const float* __restrict__ src, float* __restrict__ agg, int E) {
    int tid = threadIdx.x;               // 0..255
    int e = blockIdx.x * 2 + (tid >> 7);
    if (e >= E) return;
    int j = tid & 127;
    int h = j >> 6;
    int vs = srcidx[e], vd = dstidx[e];
    float a = exbuf[e * 2 + h] / segsum[vd * 2 + h];
    atomicAdd(&agg[(size_t)vd * 128 + j], src[(size_t)vs * 128 + j] * a);
}

// ---- out[m][d] = 0.5*((agg[m][d]+b[d]) + (agg[m][64+d]+b[64+d])) ----
__global__ void mean_bias_kernel(const float* __restrict__ agg, const float* __restrict__ bias,
                                 float* __restrict__ out, int R) {
    int t = blockIdx.x * blockDim.x + threadIdx.x;
    if (t >= R * 64) return;
    int m = t >> 6, d = t & 63;
    float v0 = agg[(size_t)m * 128 + d] + bias[d];
    float v1 = agg[(size_t)m * 128 + 64 + d] + bias[64 + d];
    out[(size_t)m * 64 + d] = 0.5f * (v0 + v1);
}

extern "C" void kernel_launch(void* const* d_in, const int* in_sizes, int n_in,
                              void* d_out, int out_size, void* d_ws, size_t ws_size,
                              hipStream_t stream) {
    const float* vfeat   = (const float*)d_in[0];
    const float* efeat   = (const float*)d_in[1];
    const int*   inc_n   = (const int*)d_in[2];
    const int*   inc_h   = (const int*)d_in[3];
    const float* W_ke    = (const float*)d_in[4];
    const float* W_qe    = (const float*)d_in[5];
    const float* attn_ke = (const float*)d_in[6];
    const float* attn_qe = (const float*)d_in[7];
    const float* bias_e  = (const float*)d_in[8];
    const float* W_kv    = (const float*)d_in[9];
    const float* W_qv    = (const float*)d_in[10];
    const float* attn_kv = (const float*)d_in[11];
    const float* attn_qv = (const float*)d_in[12];
    const float* bias_v  = (const float*)d_in[13];

    float* ws = (float*)d_ws;
    float* vke  = ws + OFF_VKE;   // later reused as vagg
    float* exb  = ws + OFF_EX;
    float* eagg = ws + OFF_EAGG;  // later reused as ekv
    float* hsum = ws + OFF_HSUM;
    float* nsum = ws + OFF_NSUM;
    float* el   = ws + OFF_EL;
    float* er   = ws + OFF_ER;
    float* el2  = ws + OFF_EL2;
    float* er2  = ws + OFF_ER2;
    float* cqe  = ws + OFF_CQE;
    float* cqv  = ws + OFF_CQV;

    float* out_v = (float*)d_out;                  // [50000, 64]
    float* out_e = (float*)d_out + (size_t)NN * 64; // [10000, 64]

    // zero eagg + hsum + nsum (contiguous region: 1,280,000 + 20,000 + 100,000)
    hipMemsetAsync(eagg, 0, (size_t)(1280000 + 20000 + 100000) * sizeof(float), stream);

    // Phase 1
    gemm128_el_kernel<4><<<dim3((NN + 3) / 4), dim3(128), 0, stream>>>(
        vfeat, W_ke, attn_ke, vke, el, NN);
    fold_attn_kernel<<<dim3(1), dim3(256), 0, stream>>>(W_qe, attn_qe, cqe);
    rows_dot_c_kernel<<<dim3((NM + 3) / 4), dim3(256), 0, stream>>>(efeat, cqe, er, NM);
    score_exp_sum_kernel<<<dim3((NE * 2 + 255) / 256), dim3(256), 0, stream>>>(
        inc_n, inc_h, el, er, exb, hsum, NE);
    scatter_kernel<<<dim3(NE / 2), dim3(256), 0, stream>>>(
        inc_n, inc_h, exb, hsum, vke, eagg, NE);
    // vke no longer needed -> zero for reuse as vagg
    hipMemsetAsync(vke, 0, (size_t)6400000 * sizeof(float), stream);
    mean_bias_kernel<<<dim3((NM * 64 + 255) / 256), dim3(256), 0, stream>>>(
        eagg, bias_e, out_e, NM);

    // Phase 2
    float* ekv  = eagg;   // reuse
    float* vagg = vke;    // reuse
    gemm64_el_kernel<4><<<dim3((NM + 3) / 4), dim3(128), 0, stream>>>(
        out_e, W_kv, attn_kv, ekv, el2, NM);
    fold_attn_kernel<<<dim3(1), dim3(256), 0, stream>>>(W_qv, attn_qv, cqv);
    rows_dot_c_kernel<<<dim3((NN + 3) / 4), dim3(256), 0, stream>>>(vfeat, cqv, er2, NN);
    // note: phase-2 softmax segments are NODES (dst = inc_node), src rows are hedges
    score_exp_sum_kernel<<<dim3((NE * 2 + 255) / 256), dim3(256), 0, stream>>>(
        inc_h, inc_n, el2, er2, exb, nsum, NE);
    scatter_kernel<<<dim3(NE / 2), dim3(256), 0, stream>>>(
        inc_h, inc_n, exb, nsum, ekv, vagg, NE);
    mean_bias_kernel<<<dim3((NN * 64 + 255) / 256), dim3(256), 0, stream>>>(
        vagg, bias_v, out_v, NN);
}

// Round 2
// 415.213 us; speedup vs baseline: 1.4349x; 1.4349x over previous
//
#include <hip/hip_runtime.h>
#include <hip/hip_bf16.h>

#define NN 50000      // nodes
#define NM 10000      // hyperedges
#define NE 500000     // incidences

// ---------------- workspace layout ----------------
// floats:
//   vke   6,400,000 @ 0
//   ekv   1,280,000 @ 6,400,000
//   el      100,000 @ 7,680,000
//   er       20,000 @ 7,780,000
//   el2      20,000 @ 7,800,000
//   er2     100,000 @ 7,820,000
//   cqe         256 @ 7,920,000
//   cqv         256 @ 7,920,256
// ints (base = float offset 7,921,000):
//   cnt_h    10,000 @ 0          (cursor reuse)
//   cnt_n    50,000 @ 10,000
//   offs_h   10,001 @ 60,000
//   offs_n   50,001 @ 70,001
//   csr_h   500,000 @ 120,002    (src node per slot, grouped by hedge)
//   csr_n   500,000 @ 620,002    (src hedge per slot, grouped by node)
static const size_t OFF_VKE  = 0;
static const size_t OFF_EKV  = 6400000;
static const size_t OFF_EL   = 7680000;
static const size_t OFF_ER   = 7780000;
static const size_t OFF_EL2  = 7800000;
static const size_t OFF_ER2  = 7820000;
static const size_t OFF_CQE  = 7920000;
static const size_t OFF_CQV  = 7920256;
static const size_t OFF_INT  = 7921000;
static const size_t I_CNT_H  = 0;
static const size_t I_CNT_N  = 10000;
static const size_t I_OFFS_H = 60000;
static const size_t I_OFFS_N = 70001;
static const size_t I_CSR_H  = 120002;
static const size_t I_CSR_N  = 620002;

// ---- GEMM [R,128] @ [128,128] -> Y [R,128], plus el[r][h] = sum_d Y*attn ----
template<int RPB>
__global__ void gemm128_el_kernel(const float* __restrict__ X, const float* __restrict__ W,
                                  const float* __restrict__ attn, float* __restrict__ Y,
                                  float* __restrict__ el, int R) {
    __shared__ float rows[RPB][128];
    int tid = threadIdx.x;              // 0..127
    int r0 = blockIdx.x * RPB;
    for (int r = 0; r < RPB; ++r) {
        int m = r0 + r;
        rows[r][tid] = (m < R) ? X[(size_t)m * 128 + tid] : 0.f;
    }
    __syncthreads();
    float acc[RPB];
    #pragma unroll
    for (int r = 0; r < RPB; ++r) acc[r] = 0.f;
    #pragma unroll 8
    for (int k = 0; k < 128; ++k) {
        float wv = W[k * 128 + tid];
        #pragma unroll
        for (int r = 0; r < RPB; ++r) acc[r] += rows[r][k] * wv;
    }
    float av = attn[tid];
    int h = tid >> 6;
    for (int r = 0; r < RPB; ++r) {
        int m = r0 + r;
        if (m < R) Y[(size_t)m * 128 + tid] = acc[r];
        float v = acc[r] * av;
        for (int off = 32; off > 0; off >>= 1) v += __shfl_down(v, off);
        if ((tid & 63) == 0 && m < R) el[m * 2 + h] = v;
    }
}

// ---- GEMM [R,64] @ [64,128] -> Y [R,128], plus el reduce ----
template<int RPB>
__global__ void gemm64_el_kernel(const float* __restrict__ X, const float* __restrict__ W,
                                 const float* __restrict__ attn, float* __restrict__ Y,
                                 float* __restrict__ el, int R) {
    __shared__ float rows[RPB][64];
    int tid = threadIdx.x;              // 0..127
    int r0 = blockIdx.x * RPB;
    for (int i = tid; i < RPB * 64; i += 128) {
        int r = i >> 6, k = i & 63;
        int m = r0 + r;
        rows[r][k] = (m < R) ? X[(size_t)m * 64 + k] : 0.f;
    }
    __syncthreads();
    float acc[RPB];
    #pragma unroll
    for (int r = 0; r < RPB; ++r) acc[r] = 0.f;
    #pragma unroll 8
    for (int k = 0; k < 64; ++k) {
        float wv = W[k * 128 + tid];
        #pragma unroll
        for (int r = 0; r < RPB; ++r) acc[r] += rows[r][k] * wv;
    }
    float av = attn[tid];
    int h = tid >> 6;
    for (int r = 0; r < RPB; ++r) {
        int m = r0 + r;
        if (m < R) Y[(size_t)m * 128 + tid] = acc[r];
        float v = acc[r] * av;
        for (int off = 32; off > 0; off >>= 1) v += __shfl_down(v, off);
        if ((tid & 63) == 0 && m < R) el[m * 2 + h] = v;
    }
}

// ---- c[h*128+k] = sum_j W[k*128 + h*64 + j] * attn[h*64+j] ----
__global__ void fold_attn_kernel(const float* __restrict__ W, const float* __restrict__ attn,
                                 float* __restrict__ c) {
    int t = threadIdx.x;                 // 0..255
    int h = t >> 7, k = t & 127;
    float s = 0.f;
    #pragma unroll 8
    for (int j = 0; j < 64; ++j) s += W[k * 128 + h * 64 + j] * attn[h * 64 + j];
    c[h * 128 + k] = s;
}

// ---- er[m][h] = X[m,:] . c[h,:], one wave per row, 4 rows/block ----
__global__ void rows_dot_c_kernel(const float* __restrict__ X, const float* __restrict__ c,
                                  float* __restrict__ er, int R) {
    int tid = threadIdx.x;               // 0..255
    int wave = tid >> 6, lane = tid & 63;
    int m = blockIdx.x * 4 + wave;
    if (m >= R) return;
    float x0 = X[(size_t)m * 128 + lane];
    float x1 = X[(size_t)m * 128 + 64 + lane];
    float a0 = x0 * c[lane]       + x1 * c[64 + lane];
    float a1 = x0 * c[128 + lane] + x1 * c[192 + lane];
    for (int off = 32; off > 0; off >>= 1) {
        a0 += __shfl_down(a0, off);
        a1 += __shfl_down(a1, off);
    }
    if (lane == 0) { er[m * 2] = a0; er[m * 2 + 1] = a1; }
}

// ---- histogram of both index arrays ----
__global__ void hist_kernel(const int* __restrict__ inc_n, const int* __restrict__ inc_h,
                            int* __restrict__ cnt_h, int* __restrict__ cnt_n, int E) {
    int t = blockIdx.x * blockDim.x + threadIdx.x;
    if (t >= E) return;
    atomicAdd(&cnt_h[inc_h[t]], 1);
    atomicAdd(&cnt_n[inc_n[t]], 1);
}

// ---- exclusive scan (single block, chunked Hillis-Steele) ----
__global__ void exscan_kernel(const int* __restrict__ cnt, int* __restrict__ offs, int n) {
    __shared__ int buf[1024];
    __shared__ int carry;
    int tid = threadIdx.x;
    if (tid == 0) carry = 0;
    __syncthreads();
    for (int base = 0; base < n; base += 1024) {
        int i = base + tid;
        int v = (i < n) ? cnt[i] : 0;
        buf[tid] = v;
        __syncthreads();
        for (int off = 1; off < 1024; off <<= 1) {
            int t2 = (tid >= off) ? buf[tid - off] : 0;
            __syncthreads();
            buf[tid] += t2;
            __syncthreads();
        }
        if (i < n) offs[i] = carry + buf[tid] - v;
        __syncthreads();
        if (tid == 0) carry += buf[1023];
        __syncthreads();
    }
    if (tid == 0) offs[n] = carry;
}

// ---- fill both CSR source lists (cursor = re-zeroed cnt arrays) ----
__global__ void csr_fill_kernel(const int* __restrict__ inc_n, const int* __restrict__ inc_h,
                                const int* __restrict__ offs_h, const int* __restrict__ offs_n,
                                int* __restrict__ cur_h, int* __restrict__ cur_n,
                                int* __restrict__ csr_h, int* __restrict__ csr_n, int E) {
    int t = blockIdx.x * blockDim.x + threadIdx.x;
    if (t >= E) return;
    int n = inc_n[t], hd = inc_h[t];
    csr_h[offs_h[hd] + atomicAdd(&cur_h[hd], 1)] = n;
    csr_n[offs_n[n]  + atomicAdd(&cur_n[n], 1)]  = hd;
}

// ---- fused gather: softmax (num+den in one pass) + aggregate + bias + head-mean ----
__global__ void gather_kernel(const int* __restrict__ offs, const int* __restrict__ csr_src,
                              const float* __restrict__ srcfeat,   // [*,128]
                              const float* __restrict__ el_src,    // [*,2]
                              const float* __restrict__ er_dst,    // [R,2]
                              const float* __restrict__ bias,      // [128]
                              float* __restrict__ out, int R) {
    __shared__ float tmp[128];
    int m = blockIdx.x;
    int j = threadIdx.x;                 // 0..127
    int h = j >> 6;
    int beg = offs[m], end = offs[m + 1];
    float er = er_dst[m * 2 + h];
    float acc = 0.f, den = 0.f;
    for (int i = beg; i < end; ++i) {
        int vs = csr_src[i];
        float s = fmaxf(el_src[vs * 2 + h] + er, 0.f);
        float ex = __expf(s);
        den += ex;
        acc += ex * srcfeat[(size_t)vs * 128 + j];
    }
    float val = (den > 0.f) ? acc / den : 0.f;
    val += bias[j];
    tmp[j] = val;
    __syncthreads();
    if (j < 64) out[(size_t)m * 64 + j] = 0.5f * (tmp[j] + tmp[j + 64]);
}

extern "C" void kernel_launch(void* const* d_in, const int* in_sizes, int n_in,
                              void* d_out, int out_size, void* d_ws, size_t ws_size,
                              hipStream_t stream) {
    const float* vfeat   = (const float*)d_in[0];
    const float* efeat   = (const float*)d_in[1];
    const int*   inc_n   = (const int*)d_in[2];
    const int*   inc_h   = (const int*)d_in[3];
    const float* W_ke    = (const float*)d_in[4];
    const float* W_qe    = (const float*)d_in[5];
    const float* attn_ke = (const float*)d_in[6];
    const float* attn_qe = (const float*)d_in[7];
    const float* bias_e  = (const float*)d_in[8];
    const float* W_kv    = (const float*)d_in[9];
    const float* W_qv    = (const float*)d_in[10];
    const float* attn_kv = (const float*)d_in[11];
    const float* attn_qv = (const float*)d_in[12];
    const float* bias_v  = (const float*)d_in[13];

    float* ws = (float*)d_ws;
    float* vke  = ws + OFF_VKE;
    float* ekv  = ws + OFF_EKV;
    float* el   = ws + OFF_EL;
    float* er   = ws + OFF_ER;
    float* el2  = ws + OFF_EL2;
    float* er2  = ws + OFF_ER2;
    float* cqe  = ws + OFF_CQE;
    float* cqv  = ws + OFF_CQV;
    int*   ib     = (int*)(ws + OFF_INT);
    int*   cnt_h  = ib + I_CNT_H;
    int*   cnt_n  = ib + I_CNT_N;
    int*   offs_h = ib + I_OFFS_H;
    int*   offs_n = ib + I_OFFS_N;
    int*   csr_h  = ib + I_CSR_H;
    int*   csr_n  = ib + I_CSR_N;

    float* out_v = (float*)d_out;                   // [50000, 64]
    float* out_e = (float*)d_out + (size_t)NN * 64; // [10000, 64]

    // ---- CSR build ----
    hipMemsetAsync(cnt_h, 0, (size_t)(NM + NN) * sizeof(int), stream);  // cnt_h+cnt_n contiguous
    hist_kernel<<<dim3((NE + 255) / 256), dim3(256), 0, stream>>>(inc_n, inc_h, cnt_h, cnt_n, NE);
    exscan_kernel<<<dim3(1), dim3(1024), 0, stream>>>(cnt_h, offs_h, NM);
    exscan_kernel<<<dim3(1), dim3(1024), 0, stream>>>(cnt_n, offs_n, NN);
    hipMemsetAsync(cnt_h, 0, (size_t)(NM + NN) * sizeof(int), stream);  // reuse as cursors
    csr_fill_kernel<<<dim3((NE + 255) / 256), dim3(256), 0, stream>>>(
        inc_n, inc_h, offs_h, offs_n, cnt_h, cnt_n, csr_h, csr_n, NE);

    // ---- Phase 1: nodes -> hyperedges ----
    gemm128_el_kernel<4><<<dim3((NN + 3) / 4), dim3(128), 0, stream>>>(
        vfeat, W_ke, attn_ke, vke, el, NN);
    fold_attn_kernel<<<dim3(1), dim3(256), 0, stream>>>(W_qe, attn_qe, cqe);
    rows_dot_c_kernel<<<dim3((NM + 3) / 4), dim3(256), 0, stream>>>(efeat, cqe, er, NM);
    gather_kernel<<<dim3(NM), dim3(128), 0, stream>>>(
        offs_h, csr_h, vke, el, er, bias_e, out_e, NM);

    // ---- Phase 2: hyperedges -> nodes ----
    gemm64_el_kernel<4><<<dim3((NM + 3) / 4), dim3(128), 0, stream>>>(
        out_e, W_kv, attn_kv, ekv, el2, NM);
    fold_attn_kernel<<<dim3(1), dim3(256), 0, stream>>>(W_qv, attn_qv, cqv);
    rows_dot_c_kernel<<<dim3((NN + 3) / 4), dim3(256), 0, stream>>>(vfeat, cqv, er2, NN);
    gather_kernel<<<dim3(NN), dim3(128), 0, stream>>>(
        offs_n, csr_n, ekv, el2, er2, bias_v, out_v, NN);
}

// Round 3
// 314.547 us; speedup vs baseline: 1.8941x; 1.3200x over previous
//
#include <hip/hip_runtime.h>
#include <hip/hip_bf16.h>

#define NN 50000      // nodes
#define NM 10000      // hyperedges
#define NE 500000     // incidences
#define NTOT (NM + NN)          // 60000 combined segments (hedges first)
#define SCAN_BS 1024
#define NBLK ((NTOT + SCAN_BS - 1) / SCAN_BS)   // 59

// ---------------- workspace layout ----------------
// floats:
//   vke   6,400,000 @ 0
//   ekv   1,280,000 @ 6,400,000
//   el      100,000 @ 7,680,000
//   er       20,000 @ 7,780,000
//   el2      20,000 @ 7,800,000
//   er2     100,000 @ 7,820,000
//   cqe         256 @ 7,920,000
//   cqv         256 @ 7,920,256
// ints (base = float offset 7,921,000):
//   cnt_all     60,000 @ 0        (hedge counts then node counts; reused as cursors)
//   offs_all    60,001 @ 60,000   (combined exclusive scan -> slots in csr_all)
//   bsum            64 @ 120,001
//   bscan           64 @ 120,065
//   csr_all  1,000,000 @ 120,129  (hedge segments: src node ids; node segments: src hedge ids)
static const size_t OFF_VKE  = 0;
static const size_t OFF_EKV  = 6400000;
static const size_t OFF_EL   = 7680000;
static const size_t OFF_ER   = 7780000;
static const size_t OFF_EL2  = 7800000;
static const size_t OFF_ER2  = 7820000;
static const size_t OFF_CQE  = 7920000;
static const size_t OFF_CQV  = 7920256;
static const size_t OFF_INT  = 7921000;
static const size_t I_CNT    = 0;
static const size_t I_OFFS   = 60000;
static const size_t I_BSUM   = 120001;
static const size_t I_BSCAN  = 120065;
static const size_t I_CSR    = 120129;

// ---- GEMM [R,128] @ [128,128] -> Y [R,128], plus el[r][h] = sum_d Y*attn ----
template<int RPB>
__global__ void gemm128_el_kernel(const float* __restrict__ X, const float* __restrict__ W,
                                  const float* __restrict__ attn, float* __restrict__ Y,
                                  float* __restrict__ el, int R) {
    __shared__ float rows[RPB][128];
    int tid = threadIdx.x;              // 0..127
    int r0 = blockIdx.x * RPB;
    for (int r = 0; r < RPB; ++r) {
        int m = r0 + r;
        rows[r][tid] = (m < R) ? X[(size_t)m * 128 + tid] : 0.f;
    }
    __syncthreads();
    float acc[RPB];
    #pragma unroll
    for (int r = 0; r < RPB; ++r) acc[r] = 0.f;
    #pragma unroll 8
    for (int k = 0; k < 128; ++k) {
        float wv = W[k * 128 + tid];
        #pragma unroll
        for (int r = 0; r < RPB; ++r) acc[r] += rows[r][k] * wv;
    }
    float av = attn[tid];
    int h = tid >> 6;
    for (int r = 0; r < RPB; ++r) {
        int m = r0 + r;
        if (m < R) Y[(size_t)m * 128 + tid] = acc[r];
        float v = acc[r] * av;
        for (int off = 32; off > 0; off >>= 1) v += __shfl_down(v, off);
        if ((tid & 63) == 0 && m < R) el[m * 2 + h] = v;
    }
}

// ---- GEMM [R,64] @ [64,128] -> Y [R,128], plus el reduce ----
template<int RPB>
__global__ void gemm64_el_kernel(const float* __restrict__ X, const float* __restrict__ W,
                                 const float* __restrict__ attn, float* __restrict__ Y,
                                 float* __restrict__ el, int R) {
    __shared__ float rows[RPB][64];
    int tid = threadIdx.x;              // 0..127
    int r0 = blockIdx.x * RPB;
    for (int i = tid; i < RPB * 64; i += 128) {
        int r = i >> 6, k = i & 63;
        int m = r0 + r;
        rows[r][k] = (m < R) ? X[(size_t)m * 64 + k] : 0.f;
    }
    __syncthreads();
    float acc[RPB];
    #pragma unroll
    for (int r = 0; r < RPB; ++r) acc[r] = 0.f;
    #pragma unroll 8
    for (int k = 0; k < 64; ++k) {
        float wv = W[k * 128 + tid];
        #pragma unroll
        for (int r = 0; r < RPB; ++r) acc[r] += rows[r][k] * wv;
    }
    float av = attn[tid];
    int h = tid >> 6;
    for (int r = 0; r < RPB; ++r) {
        int m = r0 + r;
        if (m < R) Y[(size_t)m * 128 + tid] = acc[r];
        float v = acc[r] * av;
        for (int off = 32; off > 0; off >>= 1) v += __shfl_down(v, off);
        if ((tid & 63) == 0 && m < R) el[m * 2 + h] = v;
    }
}

// ---- c[h*128+k] = sum_j W[k*128 + h*64 + j] * attn[h*64+j] ----
__global__ void fold_attn_kernel(const float* __restrict__ W, const float* __restrict__ attn,
                                 float* __restrict__ c) {
    int t = threadIdx.x;                 // 0..255
    int h = t >> 7, k = t & 127;
    float s = 0.f;
    #pragma unroll 8
    for (int j = 0; j < 64; ++j) s += W[k * 128 + h * 64 + j] * attn[h * 64 + j];
    c[h * 128 + k] = s;
}

// ---- er[m][h] = X[m,:] . c[h,:], one wave per row, 4 rows/block ----
__global__ void rows_dot_c_kernel(const float* __restrict__ X, const float* __restrict__ c,
                                  float* __restrict__ er, int R) {
    int tid = threadIdx.x;               // 0..255
    int wave = tid >> 6, lane = tid & 63;
    int m = blockIdx.x * 4 + wave;
    if (m >= R) return;
    float x0 = X[(size_t)m * 128 + lane];
    float x1 = X[(size_t)m * 128 + 64 + lane];
    float a0 = x0 * c[lane]       + x1 * c[64 + lane];
    float a1 = x0 * c[128 + lane] + x1 * c[192 + lane];
    for (int off = 32; off > 0; off >>= 1) {
        a0 += __shfl_down(a0, off);
        a1 += __shfl_down(a1, off);
    }
    if (lane == 0) { er[m * 2] = a0; er[m * 2 + 1] = a1; }
}

// ---- histogram into combined count array: [0,NM) hedges, [NM,NM+NN) nodes ----
__global__ void hist_kernel(const int* __restrict__ inc_n, const int* __restrict__ inc_h,
                            int* __restrict__ cnt, int E) {
    int t = blockIdx.x * blockDim.x + threadIdx.x;
    if (t >= E) return;
    atomicAdd(&cnt[inc_h[t]], 1);
    atomicAdd(&cnt[NM + inc_n[t]], 1);
}

// ---- hierarchical exclusive scan, step 1: per-block sums ----
__global__ void block_reduce_kernel(const int* __restrict__ cnt, int* __restrict__ bsum, int n) {
    __shared__ int wsum[16];
    int tid = threadIdx.x;
    int i = blockIdx.x * SCAN_BS + tid;
    int v = (i < n) ? cnt[i] : 0;
    for (int off = 32; off > 0; off >>= 1) v += __shfl_down(v, off);
    if ((tid & 63) == 0) wsum[tid >> 6] = v;
    __syncthreads();
    if (tid < 64) {
        int s = (tid < 16) ? wsum[tid] : 0;
        for (int off = 8; off > 0; off >>= 1) s += __shfl_down(s, off);
        if (tid == 0) bsum[blockIdx.x] = s;
    }
}

// ---- step 2: exclusive scan of block sums (<=64), plus grand total -> offs[n] ----
__global__ void scan_bsums_kernel(const int* __restrict__ bsum, int* __restrict__ bscan,
                                  int nb, int* __restrict__ offs, int n) {
    int lane = threadIdx.x;      // 64 threads, 1 wave
    int v = (lane < nb) ? bsum[lane] : 0;
    int incl = v;
    for (int d = 1; d < 64; d <<= 1) {
        int t = __shfl_up(incl, d);
        if (lane >= d) incl += t;
    }
    if (lane < nb) bscan[lane] = incl - v;
    if (lane == 63) offs[n] = incl;     // grand total
}

// ---- step 3: in-block exclusive scan + block carry -> offs ----
__global__ void block_scan_kernel(const int* __restrict__ cnt, const int* __restrict__ bscan,
                                  int* __restrict__ offs, int n) {
    __shared__ int wsum[16];
    int tid = threadIdx.x;
    int i = blockIdx.x * SCAN_BS + tid;
    int lane = tid & 63, widx = tid >> 6;
    int v = (i < n) ? cnt[i] : 0;
    int incl = v;
    for (int d = 1; d < 64; d <<= 1) {
        int t = __shfl_up(incl, d);
        if (lane >= d) incl += t;
    }
    if (lane == 63) wsum[widx] = incl;
    __syncthreads();
    if (tid < 64) {
        int s = (tid < 16) ? wsum[tid] : 0;
        int si = s;
        for (int d = 1; d < 16; d <<= 1) {
            int t = __shfl_up(si, d);
            if (tid >= d) si += t;
        }
        if (tid < 16) wsum[tid] = si - s;   // exclusive wave prefix
    }
    __syncthreads();
    if (i < n) offs[i] = bscan[blockIdx.x] + wsum[widx] + (incl - v);
}

// ---- fill combined CSR (cursors = re-zeroed cnt array) ----
__global__ void csr_fill_kernel(const int* __restrict__ inc_n, const int* __restrict__ inc_h,
                                const int* __restrict__ offs, int* __restrict__ cur,
                                int* __restrict__ csr, int E) {
    int t = blockIdx.x * blockDim.x + threadIdx.x;
    if (t >= E) return;
    int n = inc_n[t], hd = inc_h[t];
    csr[offs[hd] + atomicAdd(&cur[hd], 1)] = n;
    csr[offs[NM + n] + atomicAdd(&cur[NM + n], 1)] = hd;
}

// ---- fused gather: softmax (num+den in one pass) + aggregate + bias + head-mean ----
__global__ void gather_kernel(const int* __restrict__ offs, const int* __restrict__ csr_src,
                              const float* __restrict__ srcfeat,   // [*,128]
                              const float* __restrict__ el_src,    // [*,2]
                              const float* __restrict__ er_dst,    // [R,2]
                              const float* __restrict__ bias,      // [128]
                              float* __restrict__ out, int R) {
    __shared__ float tmp[128];
    int m = blockIdx.x;
    int j = threadIdx.x;                 // 0..127
    int h = j >> 6;
    int beg = offs[m], end = offs[m + 1];
    float er = er_dst[m * 2 + h];
    float acc = 0.f, den = 0.f;
    for (int i = beg; i < end; ++i) {
        int vs = csr_src[i];
        float s = fmaxf(el_src[vs * 2 + h] + er, 0.f);
        float ex = __expf(s);
        den += ex;
        acc += ex * srcfeat[(size_t)vs * 128 + j];
    }
    float val = (den > 0.f) ? acc / den : 0.f;
    val += bias[j];
    tmp[j] = val;
    __syncthreads();
    if (j < 64) out[(size_t)m * 64 + j] = 0.5f * (tmp[j] + tmp[j + 64]);
}

extern "C" void kernel_launch(void* const* d_in, const int* in_sizes, int n_in,
                              void* d_out, int out_size, void* d_ws, size_t ws_size,
                              hipStream_t stream) {
    const float* vfeat   = (const float*)d_in[0];
    const float* efeat   = (const float*)d_in[1];
    const int*   inc_n   = (const int*)d_in[2];
    const int*   inc_h   = (const int*)d_in[3];
    const float* W_ke    = (const float*)d_in[4];
    const float* W_qe    = (const float*)d_in[5];
    const float* attn_ke = (const float*)d_in[6];
    const float* attn_qe = (const float*)d_in[7];
    const float* bias_e  = (const float*)d_in[8];
    const float* W_kv    = (const float*)d_in[9];
    const float* W_qv    = (const float*)d_in[10];
    const float* attn_kv = (const float*)d_in[11];
    const float* attn_qv = (const float*)d_in[12];
    const float* bias_v  = (const float*)d_in[13];

    float* ws = (float*)d_ws;
    float* vke  = ws + OFF_VKE;
    float* ekv  = ws + OFF_EKV;
    float* el   = ws + OFF_EL;
    float* er   = ws + OFF_ER;
    float* el2  = ws + OFF_EL2;
    float* er2  = ws + OFF_ER2;
    float* cqe  = ws + OFF_CQE;
    float* cqv  = ws + OFF_CQV;
    int*   ib     = (int*)(ws + OFF_INT);
    int*   cnt    = ib + I_CNT;
    int*   offs   = ib + I_OFFS;
    int*   bsum   = ib + I_BSUM;
    int*   bscan  = ib + I_BSCAN;
    int*   csr    = ib + I_CSR;

    float* out_v = (float*)d_out;                   // [50000, 64]
    float* out_e = (float*)d_out + (size_t)NN * 64; // [10000, 64]

    // ---- CSR build (combined hedge+node segments) ----
    hipMemsetAsync(cnt, 0, (size_t)NTOT * sizeof(int), stream);
    hist_kernel<<<dim3((NE + 255) / 256), dim3(256), 0, stream>>>(inc_n, inc_h, cnt, NE);
    block_reduce_kernel<<<dim3(NBLK), dim3(SCAN_BS), 0, stream>>>(cnt, bsum, NTOT);
    scan_bsums_kernel<<<dim3(1), dim3(64), 0, stream>>>(bsum, bscan, NBLK, offs, NTOT);
    block_scan_kernel<<<dim3(NBLK), dim3(SCAN_BS), 0, stream>>>(cnt, bscan, offs, NTOT);
    hipMemsetAsync(cnt, 0, (size_t)NTOT * sizeof(int), stream);  // reuse as cursors
    csr_fill_kernel<<<dim3((NE + 255) / 256), dim3(256), 0, stream>>>(
        inc_n, inc_h, offs, cnt, csr, NE);

    // ---- Phase 1: nodes -> hyperedges ----
    gemm128_el_kernel<4><<<dim3((NN + 3) / 4), dim3(128), 0, stream>>>(
        vfeat, W_ke, attn_ke, vke, el, NN);
    fold_attn_kernel<<<dim3(1), dim3(256), 0, stream>>>(W_qe, attn_qe, cqe);
    rows_dot_c_kernel<<<dim3((NM + 3) / 4), dim3(256), 0, stream>>>(efeat, cqe, er, NM);
    gather_kernel<<<dim3(NM), dim3(128), 0, stream>>>(
        offs, csr, vke, el, er, bias_e, out_e, NM);

    // ---- Phase 2: hyperedges -> nodes ----
    gemm64_el_kernel<4><<<dim3((NM + 3) / 4), dim3(128), 0, stream>>>(
        out_e, W_kv, attn_kv, ekv, el2, NM);
    fold_attn_kernel<<<dim3(1), dim3(256), 0, stream>>>(W_qv, attn_qv, cqv);
    rows_dot_c_kernel<<<dim3((NN + 3) / 4), dim3(256), 0, stream>>>(vfeat, cqv, er2, NN);
    gather_kernel<<<dim3(NN), dim3(128), 0, stream>>>(
        offs + NM, csr, ekv, el2, er2, bias_v, out_v, NN);
}

// Round 4
// 260.613 us; speedup vs baseline: 2.2860x; 1.2069x over previous
//
#include <hip/hip_runtime.h>
#include <hip/hip_bf16.h>

#define NN 50000      // nodes
#define NM 10000      // hyperedges
#define NE 500000     // incidences
#define NTOT (NM + NN)          // 60000 combined segments (hedges first)
#define SCAN_BS 1024
#define NBLK ((NTOT + SCAN_BS - 1) / SCAN_BS)   // 59

// ---------------- workspace layout ----------------
// float-sized slots:
//   vke(bf16 u32x64/row) 3,200,000 @ 0
//   ekv(bf16 u32x64/row)   640,000 @ 3,200,000
//   el      100,000 @ 3,840,000
//   er       20,000 @ 3,940,000
//   el2      20,000 @ 3,960,000
//   er2     100,000 @ 3,980,000
//   cqe         256 @ 4,080,000
//   cqv         256 @ 4,080,256
// ints (base = float offset 4,081,000):
//   cnt     60,000 @ 0        (hedge counts then node counts; reused as cursors)
//   offs    60,001 @ 60,000
//   bsum        64 @ 120,001
//   bscan       64 @ 120,065
//   csr  1,000,000 @ 120,129
static const size_t OFF_VKE  = 0;
static const size_t OFF_EKV  = 3200000;
static const size_t OFF_EL   = 3840000;
static const size_t OFF_ER   = 3940000;
static const size_t OFF_EL2  = 3960000;
static const size_t OFF_ER2  = 3980000;
static const size_t OFF_CQE  = 4080000;
static const size_t OFF_CQV  = 4080256;
static const size_t OFF_INT  = 4081000;
static const size_t I_CNT    = 0;
static const size_t I_OFFS   = 60000;
static const size_t I_BSUM   = 120001;
static const size_t I_BSCAN  = 120065;
static const size_t I_CSR    = 120129;

__device__ __forceinline__ unsigned short f2bf(float f) {
    unsigned int u = __float_as_uint(f);
    unsigned int r = (u + 0x7fffu + ((u >> 16) & 1u)) >> 16;   // RNE
    return (unsigned short)r;
}
__device__ __forceinline__ float bflo(unsigned int p) { return __uint_as_float(p << 16); }
__device__ __forceinline__ float bfhi(unsigned int p) { return __uint_as_float(p & 0xffff0000u); }

// ---- GEMM [R,128] @ [128,128] -> Ybf16 [R,128], el[r][h]=sum Y*attn, er2[r][h]=X.cq ----
template<int RPB>
__global__ void gemm128_el_kernel(const float* __restrict__ X, const float* __restrict__ W,
                                  const float* __restrict__ attn, const float* __restrict__ cq,
                                  unsigned short* __restrict__ Y, float* __restrict__ el,
                                  float* __restrict__ er2, int R) {
    __shared__ float rows[RPB][128];
    __shared__ float part[2][RPB][2];
    int tid = threadIdx.x;              // 0..127
    int wid = tid >> 6, lane = tid & 63;
    int r0 = blockIdx.x * RPB;
    for (int r = 0; r < RPB; ++r) {
        int m = r0 + r;
        rows[r][tid] = (m < R) ? X[(size_t)m * 128 + tid] : 0.f;
    }
    __syncthreads();
    float acc[RPB];
    #pragma unroll
    for (int r = 0; r < RPB; ++r) acc[r] = 0.f;
    #pragma unroll 8
    for (int k = 0; k < 128; ++k) {
        float wv = W[k * 128 + tid];
        #pragma unroll
        for (int r = 0; r < RPB; ++r) acc[r] += rows[r][k] * wv;
    }
    float av = attn[tid];
    int h = wid;
    for (int r = 0; r < RPB; ++r) {
        int m = r0 + r;
        if (m < R) Y[(size_t)m * 128 + tid] = f2bf(acc[r]);
        float v = acc[r] * av;
        for (int off = 32; off > 0; off >>= 1) v += __shfl_down(v, off);
        if (lane == 0 && m < R) el[m * 2 + h] = v;
    }
    // er2[m][h] = X[m,:] . cq[h,:]
    for (int r = 0; r < RPB; ++r) {
        float x = rows[r][tid];
        float p0 = x * cq[tid];
        float p1 = x * cq[128 + tid];
        for (int off = 32; off > 0; off >>= 1) {
            p0 += __shfl_down(p0, off);
            p1 += __shfl_down(p1, off);
        }
        if (lane == 0) { part[wid][r][0] = p0; part[wid][r][1] = p1; }
    }
    __syncthreads();
    if (tid < RPB * 2) {
        int r = tid >> 1, hh = tid & 1;
        int m = r0 + r;
        if (m < R) er2[m * 2 + hh] = part[0][r][hh] + part[1][r][hh];
    }
}

// ---- GEMM [R,64] @ [64,128] -> Ybf16 [R,128], plus el reduce ----
template<int RPB>
__global__ void gemm64_el_kernel(const float* __restrict__ X, const float* __restrict__ W,
                                 const float* __restrict__ attn, unsigned short* __restrict__ Y,
                                 float* __restrict__ el, int R) {
    __shared__ float rows[RPB][64];
    int tid = threadIdx.x;              // 0..127
    int r0 = blockIdx.x * RPB;
    for (int i = tid; i < RPB * 64; i += 128) {
        int r = i >> 6, k = i & 63;
        int m = r0 + r;
        rows[r][k] = (m < R) ? X[(size_t)m * 64 + k] : 0.f;
    }
    __syncthreads();
    float acc[RPB];
    #pragma unroll
    for (int r = 0; r < RPB; ++r) acc[r] = 0.f;
    #pragma unroll 8
    for (int k = 0; k < 64; ++k) {
        float wv = W[k * 128 + tid];
        #pragma unroll
        for (int r = 0; r < RPB; ++r) acc[r] += rows[r][k] * wv;
    }
    float av = attn[tid];
    int h = tid >> 6;
    for (int r = 0; r < RPB; ++r) {
        int m = r0 + r;
        if (m < R) Y[(size_t)m * 128 + tid] = f2bf(acc[r]);
        float v = acc[r] * av;
        for (int off = 32; off > 0; off >>= 1) v += __shfl_down(v, off);
        if ((tid & 63) == 0 && m < R) el[m * 2 + h] = v;
    }
}

// ---- both attn folds in one launch: c[h*128+k] = sum_j W[k*128+h*64+j]*attn[h*64+j] ----
__global__ void fold_attn_kernel(const float* __restrict__ Wa, const float* __restrict__ aa,
                                 float* __restrict__ ca,
                                 const float* __restrict__ Wb, const float* __restrict__ ab,
                                 float* __restrict__ cb) {
    const float* W    = blockIdx.x ? Wb : Wa;
    const float* attn = blockIdx.x ? ab : aa;
    float*       c    = blockIdx.x ? cb : ca;
    int t = threadIdx.x;                 // 0..255
    int h = t >> 7, k = t & 127;
    float s = 0.f;
    #pragma unroll 8
    for (int j = 0; j < 64; ++j) s += W[k * 128 + h * 64 + j] * attn[h * 64 + j];
    c[h * 128 + k] = s;
}

// ---- er[m][h] = X[m,:128] . c[h,:], one wave per row ----
__global__ void rows_dot_c_kernel(const float* __restrict__ X, const float* __restrict__ c,
                                  float* __restrict__ er, int R) {
    int tid = threadIdx.x;               // 0..255
    int wave = tid >> 6, lane = tid & 63;
    int m = blockIdx.x * 4 + wave;
    if (m >= R) return;
    float x0 = X[(size_t)m * 128 + lane];
    float x1 = X[(size_t)m * 128 + 64 + lane];
    float a0 = x0 * c[lane]       + x1 * c[64 + lane];
    float a1 = x0 * c[128 + lane] + x1 * c[192 + lane];
    for (int off = 32; off > 0; off >>= 1) {
        a0 += __shfl_down(a0, off);
        a1 += __shfl_down(a1, off);
    }
    if (lane == 0) { er[m * 2] = a0; er[m * 2 + 1] = a1; }
}

// ---- histogram into combined count array: [0,NM) hedges, [NM,NM+NN) nodes ----
__global__ void hist_kernel(const int* __restrict__ inc_n, const int* __restrict__ inc_h,
                            int* __restrict__ cnt, int E) {
    int t = blockIdx.x * blockDim.x + threadIdx.x;
    if (t >= E) return;
    atomicAdd(&cnt[inc_h[t]], 1);
    atomicAdd(&cnt[NM + inc_n[t]], 1);
}

// ---- hierarchical exclusive scan ----
__global__ void block_reduce_kernel(const int* __restrict__ cnt, int* __restrict__ bsum, int n) {
    __shared__ int wsum[16];
    int tid = threadIdx.x;
    int i = blockIdx.x * SCAN_BS + tid;
    int v = (i < n) ? cnt[i] : 0;
    for (int off = 32; off > 0; off >>= 1) v += __shfl_down(v, off);
    if ((tid & 63) == 0) wsum[tid >> 6] = v;
    __syncthreads();
    if (tid < 64) {
        int s = (tid < 16) ? wsum[tid] : 0;
        for (int off = 8; off > 0; off >>= 1) s += __shfl_down(s, off);
        if (tid == 0) bsum[blockIdx.x] = s;
    }
}

__global__ void scan_bsums_kernel(const int* __restrict__ bsum, int* __restrict__ bscan,
                                  int nb, int* __restrict__ offs, int n) {
    int lane = threadIdx.x;      // 64 threads
    int v = (lane < nb) ? bsum[lane] : 0;
    int incl = v;
    for (int d = 1; d < 64; d <<= 1) {
        int t = __shfl_up(incl, d);
        if (lane >= d) incl += t;
    }
    if (lane < nb) bscan[lane] = incl - v;
    if (lane == 63) offs[n] = incl;
}

__global__ void block_scan_kernel(const int* __restrict__ cnt, const int* __restrict__ bscan,
                                  int* __restrict__ offs, int n) {
    __shared__ int wsum[16];
    int tid = threadIdx.x;
    int i = blockIdx.x * SCAN_BS + tid;
    int lane = tid & 63, widx = tid >> 6;
    int v = (i < n) ? cnt[i] : 0;
    int incl = v;
    for (int d = 1; d < 64; d <<= 1) {
        int t = __shfl_up(incl, d);
        if (lane >= d) incl += t;
    }
    if (lane == 63) wsum[widx] = incl;
    __syncthreads();
    if (tid < 64) {
        int s = (tid < 16) ? wsum[tid] : 0;
        int si = s;
        for (int d = 1; d < 16; d <<= 1) {
            int t = __shfl_up(si, d);
            if (tid >= d) si += t;
        }
        if (tid < 16) wsum[tid] = si - s;
    }
    __syncthreads();
    if (i < n) offs[i] = bscan[blockIdx.x] + wsum[widx] + (incl - v);
}

// ---- fill combined CSR ----
__global__ void csr_fill_kernel(const int* __restrict__ inc_n, const int* __restrict__ inc_h,
                                const int* __restrict__ offs, int* __restrict__ cur,
                                int* __restrict__ csr, int E) {
    int t = blockIdx.x * blockDim.x + threadIdx.x;
    if (t >= E) return;
    int n = inc_n[t], hd = inc_h[t];
    csr[offs[hd] + atomicAdd(&cur[hd], 1)] = n;
    csr[offs[NM + n] + atomicAdd(&cur[NM + n], 1)] = hd;
}

// ---- fused gather: wave per dest row, bf16x2 lanes, softmax+agg+bias+head-mean ----
__global__ void gather_kernel(const int* __restrict__ offs, const int* __restrict__ csr,
                              const unsigned int* __restrict__ src32,  // [*,64] bf16x2
                              const float* __restrict__ el_src,        // [*,2]
                              const float* __restrict__ er_dst,        // [R,2]
                              const float* __restrict__ bias,          // [128]
                              float* __restrict__ out, int R) {
    int wave = threadIdx.x >> 6, lane = threadIdx.x & 63;
    int m = blockIdx.x * 4 + wave;
    if (m >= R) return;
    int h = lane >> 5;                  // lanes 0-31: head0 elems, 32-63: head1
    int beg = offs[m], end = offs[m + 1];
    float er = er_dst[m * 2 + h];
    float acc0 = 0.f, acc1 = 0.f, den = 0.f;
    int i = beg;
    for (; i + 1 < end; i += 2) {
        int vs0 = csr[i], vs1 = csr[i + 1];
        unsigned int p0 = src32[(size_t)vs0 * 64 + lane];
        unsigned int p1 = src32[(size_t)vs1 * 64 + lane];
        float e0 = el_src[vs0 * 2 + h];
        float e1 = el_src[vs1 * 2 + h];
        float ex0 = __expf(fmaxf(e0 + er, 0.f));
        float ex1 = __expf(fmaxf(e1 + er, 0.f));
        den += ex0 + ex1;
        acc0 += ex0 * bflo(p0) + ex1 * bflo(p1);
        acc1 += ex0 * bfhi(p0) + ex1 * bfhi(p1);
    }
    if (i < end) {
        int vs = csr[i];
        unsigned int p = src32[(size_t)vs * 64 + lane];
        float ex = __expf(fmaxf(el_src[vs * 2 + h] + er, 0.f));
        den += ex;
        acc0 += ex * bflo(p);
        acc1 += ex * bfhi(p);
    }
    float inv = (den > 0.f) ? 1.f / den : 0.f;
    acc0 *= inv; acc1 *= inv;
    float b0 = __shfl_down(acc0, 32);
    float b1 = __shfl_down(acc1, 32);
    if (lane < 32) {
        int e0 = 2 * lane, e1 = 2 * lane + 1;
        float o0 = 0.5f * (acc0 + b0 + bias[e0] + bias[64 + e0]);
        float o1 = 0.5f * (acc1 + b1 + bias[e1] + bias[64 + e1]);
        reinterpret_cast<float2*>(out + (size_t)m * 64)[lane] = make_float2(o0, o1);
    }
}

extern "C" void kernel_launch(void* const* d_in, const int* in_sizes, int n_in,
                              void* d_out, int out_size, void* d_ws, size_t ws_size,
                              hipStream_t stream) {
    const float* vfeat   = (const float*)d_in[0];
    const float* efeat   = (const float*)d_in[1];
    const int*   inc_n   = (const int*)d_in[2];
    const int*   inc_h   = (const int*)d_in[3];
    const float* W_ke    = (const float*)d_in[4];
    const float* W_qe    = (const float*)d_in[5];
    const float* attn_ke = (const float*)d_in[6];
    const float* attn_qe = (const float*)d_in[7];
    const float* bias_e  = (const float*)d_in[8];
    const float* W_kv    = (const float*)d_in[9];
    const float* W_qv    = (const float*)d_in[10];
    const float* attn_kv = (const float*)d_in[11];
    const float* attn_qv = (const float*)d_in[12];
    const float* bias_v  = (const float*)d_in[13];

    float* ws = (float*)d_ws;
    unsigned int*   vke = (unsigned int*)(ws + OFF_VKE);
    unsigned int*   ekv = (unsigned int*)(ws + OFF_EKV);
    float* el   = ws + OFF_EL;
    float* er   = ws + OFF_ER;
    float* el2  = ws + OFF_EL2;
    float* er2  = ws + OFF_ER2;
    float* cqe  = ws + OFF_CQE;
    float* cqv  = ws + OFF_CQV;
    int*   ib     = (int*)(ws + OFF_INT);
    int*   cnt    = ib + I_CNT;
    int*   offs   = ib + I_OFFS;
    int*   bsum   = ib + I_BSUM;
    int*   bscan  = ib + I_BSCAN;
    int*   csr    = ib + I_CSR;

    float* out_v = (float*)d_out;                   // [50000, 64]
    float* out_e = (float*)d_out + (size_t)NN * 64; // [10000, 64]

    // ---- CSR build (combined hedge+node segments) ----
    hipMemsetAsync(cnt, 0, (size_t)NTOT * sizeof(int), stream);
    hist_kernel<<<dim3((NE + 255) / 256), dim3(256), 0, stream>>>(inc_n, inc_h, cnt, NE);
    block_reduce_kernel<<<dim3(NBLK), dim3(SCAN_BS), 0, stream>>>(cnt, bsum, NTOT);
    scan_bsums_kernel<<<dim3(1), dim3(64), 0, stream>>>(bsum, bscan, NBLK, offs, NTOT);
    block_scan_kernel<<<dim3(NBLK), dim3(SCAN_BS), 0, stream>>>(cnt, bscan, offs, NTOT);
    hipMemsetAsync(cnt, 0, (size_t)NTOT * sizeof(int), stream);  // reuse as cursors
    csr_fill_kernel<<<dim3((NE + 255) / 256), dim3(256), 0, stream>>>(
        inc_n, inc_h, offs, cnt, csr, NE);

    // ---- attn folds (both phases, one launch) ----
    fold_attn_kernel<<<dim3(2), dim3(256), 0, stream>>>(W_qe, attn_qe, cqe, W_qv, attn_qv, cqv);

    // ---- Phase 1: nodes -> hyperedges ----
    rows_dot_c_kernel<<<dim3((NM + 3) / 4), dim3(256), 0, stream>>>(efeat, cqe, er, NM);
    gemm128_el_kernel<4><<<dim3((NN + 3) / 4), dim3(128), 0, stream>>>(
        vfeat, W_ke, attn_ke, cqv, (unsigned short*)vke, el, er2, NN);
    gather_kernel<<<dim3((NM + 3) / 4), dim3(256), 0, stream>>>(
        offs, csr, vke, el, er, bias_e, out_e, NM);

    // ---- Phase 2: hyperedges -> nodes ----
    gemm64_el_kernel<4><<<dim3((NM + 3) / 4), dim3(128), 0, stream>>>(
        out_e, W_kv, attn_kv, (unsigned short*)ekv, el2, NM);
    gather_kernel<<<dim3((NN + 3) / 4), dim3(256), 0, stream>>>(
        offs + NM, csr, ekv, el2, er2, bias_v, out_v, NN);
}

// Round 5
// 240.376 us; speedup vs baseline: 2.4785x; 1.0842x over previous
//
#include <hip/hip_runtime.h>
#include <hip/hip_bf16.h>

#define NN 50000      // nodes
#define NM 10000      // hyperedges
#define NE 500000     // incidences
#define NTOT (NM + NN)          // 60000 combined segments (hedges first)
#define SCAN_BS 1024
#define NBLK ((NTOT + SCAN_BS - 1) / SCAN_BS)   // 59

typedef short bf16x8 __attribute__((ext_vector_type(8)));
typedef unsigned short u16x8 __attribute__((ext_vector_type(8)));
typedef float f32x4 __attribute__((ext_vector_type(4)));

// ---------------- workspace layout ----------------
// float-sized slots:
//   vke(bf16 u32x64/row) 3,200,000 @ 0
//   ekv(bf16 u32x64/row)   640,000 @ 3,200,000
//   el      100,000 @ 3,840,000
//   er       20,000 @ 3,940,000
//   el2      20,000 @ 3,960,000
//   er2     100,000 @ 3,980,000
//   cqe         256 @ 4,080,000
//   cqv         256 @ 4,080,256
//   Wt (bf16 16384)  8,192 float slots @ 4,080,512
// ints (base = float offset 4,089,000):
//   cnt     60,000 @ 0        (reused as cursors)
//   offs    60,001 @ 60,000
//   bsum        64 @ 120,001
//   bscan       64 @ 120,065
//   csr  1,000,000 @ 120,129
static const size_t OFF_VKE  = 0;
static const size_t OFF_EKV  = 3200000;
static const size_t OFF_EL   = 3840000;
static const size_t OFF_ER   = 3940000;
static const size_t OFF_EL2  = 3960000;
static const size_t OFF_ER2  = 3980000;
static const size_t OFF_CQE  = 4080000;
static const size_t OFF_CQV  = 4080256;
static const size_t OFF_WT   = 4080512;
static const size_t OFF_INT  = 4089000;
static const size_t I_CNT    = 0;
static const size_t I_OFFS   = 60000;
static const size_t I_BSUM   = 120001;
static const size_t I_BSCAN  = 120065;
static const size_t I_CSR    = 120129;

__device__ __forceinline__ unsigned short f2bf(float f) {
    unsigned int u = __float_as_uint(f);
    unsigned int r = (u + 0x7fffu + ((u >> 16) & 1u)) >> 16;   // RNE
    return (unsigned short)r;
}
__device__ __forceinline__ float bflo(unsigned int p) { return __uint_as_float(p << 16); }
__device__ __forceinline__ float bfhi(unsigned int p) { return __uint_as_float(p & 0xffff0000u); }

// ---- W [128 in][128 out] f32 -> Wt [out][in] bf16 ----
__global__ void convW_kernel(const float* __restrict__ W, unsigned short* __restrict__ Wt) {
    int col = blockIdx.x, k = threadIdx.x;           // 128 blocks x 128 threads
    Wt[col * 128 + k] = f2bf(W[k * 128 + col]);
}

// ---- MFMA GEMM: X[R,128]f32 @ Wt^T -> Y[R,128]bf16, + el (Y.attn) + er2 (X.cq) ----
// block: 256 threads (4 waves), 64 rows; full K=128 in LDS, swizzled bf16.
__global__ void mfma_gemm128_kernel(const float* __restrict__ X,
                                    const unsigned short* __restrict__ Wt,
                                    const float* __restrict__ attn,
                                    const float* __restrict__ cq,
                                    unsigned short* __restrict__ Y,
                                    float* __restrict__ el,
                                    float* __restrict__ er2, int R) {
    __shared__ unsigned short Abuf[64 * 128];    // 16 KB, idx ^ ((row&7)<<3)
    __shared__ unsigned short Wbuf[128 * 128];   // 32 KB, idx ^ ((col&7)<<3)
    int tid = threadIdx.x;
    int m0 = blockIdx.x * 64;

    // ---- stage W (bf16 global, coalesced) ----
    {
        const u16x8* Wg = reinterpret_cast<const u16x8*>(Wt);
        #pragma unroll
        for (int i = 0; i < 8; ++i) {
            int idx16 = i * 256 + tid;           // 2048 x 16B
            u16x8 w8 = Wg[idx16];
            int col = idx16 >> 4, kb = idx16 & 15;
            int us = (col * 128 + kb * 8) ^ ((col & 7) << 3);
            *reinterpret_cast<u16x8*>(&Wbuf[us]) = w8;
        }
    }
    // ---- stage X (f32 -> bf16) + er2 partial dot with cq ----
    {
        int r = tid >> 2, q = tid & 3;           // 4 threads per row, 32 cols each
        int m = m0 + r;
        float p0 = 0.f, p1 = 0.f;
        if (m < R) {
            const float4* Xr = reinterpret_cast<const float4*>(X + (size_t)m * 128 + q * 32);
            #pragma unroll
            for (int i2 = 0; i2 < 4; ++i2) {
                float4 u = Xr[i2 * 2], v = Xr[i2 * 2 + 1];
                int k0 = q * 32 + i2 * 8;
                u16x8 w8;
                w8[0] = f2bf(u.x); w8[1] = f2bf(u.y); w8[2] = f2bf(u.z); w8[3] = f2bf(u.w);
                w8[4] = f2bf(v.x); w8[5] = f2bf(v.y); w8[6] = f2bf(v.z); w8[7] = f2bf(v.w);
                int us = (r * 128 + k0) ^ ((r & 7) << 3);
                *reinterpret_cast<u16x8*>(&Abuf[us]) = w8;
                p0 += u.x * cq[k0] + u.y * cq[k0 + 1] + u.z * cq[k0 + 2] + u.w * cq[k0 + 3]
                    + v.x * cq[k0 + 4] + v.y * cq[k0 + 5] + v.z * cq[k0 + 6] + v.w * cq[k0 + 7];
                p1 += u.x * cq[128 + k0] + u.y * cq[128 + k0 + 1] + u.z * cq[128 + k0 + 2] + u.w * cq[128 + k0 + 3]
                    + v.x * cq[128 + k0 + 4] + v.y * cq[128 + k0 + 5] + v.z * cq[128 + k0 + 6] + v.w * cq[128 + k0 + 7];
            }
        } else {
            u16x8 z = {0, 0, 0, 0, 0, 0, 0, 0};
            #pragma unroll
            for (int i2 = 0; i2 < 4; ++i2) {
                int us = (r * 128 + q * 32 + i2 * 8) ^ ((r & 7) << 3);
                *reinterpret_cast<u16x8*>(&Abuf[us]) = z;
            }
        }
        p0 += __shfl_xor(p0, 1); p0 += __shfl_xor(p0, 2);
        p1 += __shfl_xor(p1, 1); p1 += __shfl_xor(p1, 2);
        if (q == 0 && m < R)
            reinterpret_cast<float2*>(er2 + (size_t)m * 2)[0] = make_float2(p0, p1);
    }
    __syncthreads();

    // ---- MFMA: wave w -> rows [w*16, w*16+16), 8 col-tiles, 4 K-steps ----
    int l = tid & 63, w = tid >> 6;
    int lrow = w * 16 + (l & 15);
    f32x4 acc[8];
    #pragma unroll
    for (int ct = 0; ct < 8; ++ct) acc[ct] = (f32x4){0.f, 0.f, 0.f, 0.f};
    #pragma unroll
    for (int s = 0; s < 4; ++s) {
        int aidx = (lrow * 128 + s * 32 + (l >> 4) * 8) ^ ((lrow & 7) << 3);
        bf16x8 af = *reinterpret_cast<const bf16x8*>(&Abuf[aidx]);
        #pragma unroll
        for (int ct = 0; ct < 8; ++ct) {
            int col = ct * 16 + (l & 15);
            int bidx = (col * 128 + s * 32 + (l >> 4) * 8) ^ ((col & 7) << 3);
            bf16x8 bf = *reinterpret_cast<const bf16x8*>(&Wbuf[bidx]);
            acc[ct] = __builtin_amdgcn_mfma_f32_16x16x32_bf16(af, bf, acc[ct], 0, 0, 0);
        }
    }

    // ---- epilogue: Y bf16 store, el reduce ----
    float av[8];
    #pragma unroll
    for (int ct = 0; ct < 8; ++ct) av[ct] = attn[ct * 16 + (l & 15)];
    #pragma unroll
    for (int r = 0; r < 4; ++r) {
        int m = m0 + w * 16 + (l >> 4) * 4 + r;
        bool ok = (m < R);
        #pragma unroll
        for (int ct = 0; ct < 8; ++ct)
            if (ok) Y[(size_t)m * 128 + ct * 16 + (l & 15)] = f2bf(acc[ct][r]);
        #pragma unroll
        for (int h = 0; h < 2; ++h) {
            float p = acc[h * 4][r] * av[h * 4] + acc[h * 4 + 1][r] * av[h * 4 + 1]
                    + acc[h * 4 + 2][r] * av[h * 4 + 2] + acc[h * 4 + 3][r] * av[h * 4 + 3];
            p += __shfl_xor(p, 1); p += __shfl_xor(p, 2);
            p += __shfl_xor(p, 4); p += __shfl_xor(p, 8);
            if ((l & 15) == 0 && ok) el[(size_t)m * 2 + h] = p;
        }
    }
}

// ---- GEMM [R,64] @ [64,128] -> Ybf16 [R,128], plus el reduce (vector; small R) ----
template<int RPB>
__global__ void gemm64_el_kernel(const float* __restrict__ X, const float* __restrict__ W,
                                 const float* __restrict__ attn, unsigned short* __restrict__ Y,
                                 float* __restrict__ el, int R) {
    __shared__ float rows[RPB][64];
    int tid = threadIdx.x;              // 0..127
    int r0 = blockIdx.x * RPB;
    for (int i = tid; i < RPB * 64; i += 128) {
        int r = i >> 6, k = i & 63;
        int m = r0 + r;
        rows[r][k] = (m < R) ? X[(size_t)m * 64 + k] : 0.f;
    }
    __syncthreads();
    float acc[RPB];
    #pragma unroll
    for (int r = 0; r < RPB; ++r) acc[r] = 0.f;
    #pragma unroll 8
    for (int k = 0; k < 64; ++k) {
        float wv = W[k * 128 + tid];
        #pragma unroll
        for (int r = 0; r < RPB; ++r) acc[r] += rows[r][k] * wv;
    }
    float av = attn[tid];
    int h = tid >> 6;
    for (int r = 0; r < RPB; ++r) {
        int m = r0 + r;
        if (m < R) Y[(size_t)m * 128 + tid] = f2bf(acc[r]);
        float v = acc[r] * av;
        for (int off = 32; off > 0; off >>= 1) v += __shfl_down(v, off);
        if ((tid & 63) == 0 && m < R) el[m * 2 + h] = v;
    }
}

// ---- both attn folds in one launch ----
__global__ void fold_attn_kernel(const float* __restrict__ Wa, const float* __restrict__ aa,
                                 float* __restrict__ ca,
                                 const float* __restrict__ Wb, const float* __restrict__ ab,
                                 float* __restrict__ cb) {
    const float* W    = blockIdx.x ? Wb : Wa;
    const float* attn = blockIdx.x ? ab : aa;
    float*       c    = blockIdx.x ? cb : ca;
    int t = threadIdx.x;                 // 0..255
    int h = t >> 7, k = t & 127;
    float s = 0.f;
    #pragma unroll 8
    for (int j = 0; j < 64; ++j) s += W[k * 128 + h * 64 + j] * attn[h * 64 + j];
    c[h * 128 + k] = s;
}

// ---- er[m][h] = X[m,:128] . c[h,:], one wave per row ----
__global__ void rows_dot_c_kernel(const float* __restrict__ X, const float* __restrict__ c,
                                  float* __restrict__ er, int R) {
    int tid = threadIdx.x;               // 0..255
    int wave = tid >> 6, lane = tid & 63;
    int m = blockIdx.x * 4 + wave;
    if (m >= R) return;
    float x0 = X[(size_t)m * 128 + lane];
    float x1 = X[(size_t)m * 128 + 64 + lane];
    float a0 = x0 * c[lane]       + x1 * c[64 + lane];
    float a1 = x0 * c[128 + lane] + x1 * c[192 + lane];
    for (int off = 32; off > 0; off >>= 1) {
        a0 += __shfl_down(a0, off);
        a1 += __shfl_down(a1, off);
    }
    if (lane == 0) { er[m * 2] = a0; er[m * 2 + 1] = a1; }
}

// ---- histogram into combined count array ----
__global__ void hist_kernel(const int* __restrict__ inc_n, const int* __restrict__ inc_h,
                            int* __restrict__ cnt, int E) {
    int t = blockIdx.x * blockDim.x + threadIdx.x;
    if (t >= E) return;
    atomicAdd(&cnt[inc_h[t]], 1);
    atomicAdd(&cnt[NM + inc_n[t]], 1);
}

// ---- hierarchical exclusive scan ----
__global__ void block_reduce_kernel(const int* __restrict__ cnt, int* __restrict__ bsum, int n) {
    __shared__ int wsum[16];
    int tid = threadIdx.x;
    int i = blockIdx.x * SCAN_BS + tid;
    int v = (i < n) ? cnt[i] : 0;
    for (int off = 32; off > 0; off >>= 1) v += __shfl_down(v, off);
    if ((tid & 63) == 0) wsum[tid >> 6] = v;
    __syncthreads();
    if (tid < 64) {
        int s = (tid < 16) ? wsum[tid] : 0;
        for (int off = 8; off > 0; off >>= 1) s += __shfl_down(s, off);
        if (tid == 0) bsum[blockIdx.x] = s;
    }
}

__global__ void scan_bsums_kernel(const int* __restrict__ bsum, int* __restrict__ bscan,
                                  int nb, int* __restrict__ offs, int n) {
    int lane = threadIdx.x;      // 64 threads
    int v = (lane < nb) ? bsum[lane] : 0;
    int incl = v;
    for (int d = 1; d < 64; d <<= 1) {
        int t = __shfl_up(incl, d);
        if (lane >= d) incl += t;
    }
    if (lane < nb) bscan[lane] = incl - v;
    if (lane == 63) offs[n] = incl;
}

__global__ void block_scan_kernel(const int* __restrict__ cnt, const int* __restrict__ bscan,
                                  int* __restrict__ offs, int n) {
    __shared__ int wsum[16];
    int tid = threadIdx.x;
    int i = blockIdx.x * SCAN_BS + tid;
    int lane = tid & 63, widx = tid >> 6;
    int v = (i < n) ? cnt[i] : 0;
    int incl = v;
    for (int d = 1; d < 64; d <<= 1) {
        int t = __shfl_up(incl, d);
        if (lane >= d) incl += t;
    }
    if (lane == 63) wsum[widx] = incl;
    __syncthreads();
    if (tid < 64) {
        int s = (tid < 16) ? wsum[tid] : 0;
        int si = s;
        for (int d = 1; d < 16; d <<= 1) {
            int t = __shfl_up(si, d);
            if (tid >= d) si += t;
        }
        if (tid < 16) wsum[tid] = si - s;
    }
    __syncthreads();
    if (i < n) offs[i] = bscan[blockIdx.x] + wsum[widx] + (incl - v);
}

// ---- fill combined CSR ----
__global__ void csr_fill_kernel(const int* __restrict__ inc_n, const int* __restrict__ inc_h,
                                const int* __restrict__ offs, int* __restrict__ cur,
                                int* __restrict__ csr, int E) {
    int t = blockIdx.x * blockDim.x + threadIdx.x;
    if (t >= E) return;
    int n = inc_n[t], hd = inc_h[t];
    csr[offs[hd] + atomicAdd(&cur[hd], 1)] = n;
    csr[offs[NM + n] + atomicAdd(&cur[NM + n], 1)] = hd;
}

// ---- fused gather: wave per dest row, bf16x2 lanes, softmax+agg+bias+head-mean ----
__global__ void gather_kernel(const int* __restrict__ offs, const int* __restrict__ csr,
                              const unsigned int* __restrict__ src32,  // [*,64] bf16x2
                              const float* __restrict__ el_src,        // [*,2]
                              const float* __restrict__ er_dst,        // [R,2]
                              const float* __restrict__ bias,          // [128]
                              float* __restrict__ out, int R) {
    int wave = threadIdx.x >> 6, lane = threadIdx.x & 63;
    int m = blockIdx.x * 4 + wave;
    if (m >= R) return;
    int h = lane >> 5;                  // lanes 0-31: head0 elems, 32-63: head1
    int beg = offs[m], end = offs[m + 1];
    float er = er_dst[m * 2 + h];
    float acc0 = 0.f, acc1 = 0.f, den = 0.f;
    int i = beg;
    for (; i + 1 < end; i += 2) {
        int vs0 = csr[i], vs1 = csr[i + 1];
        unsigned int p0 = src32[(size_t)vs0 * 64 + lane];
        unsigned int p1 = src32[(size_t)vs1 * 64 + lane];
        float e0 = el_src[vs0 * 2 + h];
        float e1 = el_src[vs1 * 2 + h];
        float ex0 = __expf(fmaxf(e0 + er, 0.f));
        float ex1 = __expf(fmaxf(e1 + er, 0.f));
        den += ex0 + ex1;
        acc0 += ex0 * bflo(p0) + ex1 * bflo(p1);
        acc1 += ex0 * bfhi(p0) + ex1 * bfhi(p1);
    }
    if (i < end) {
        int vs = csr[i];
        unsigned int p = src32[(size_t)vs * 64 + lane];
        float ex = __expf(fmaxf(el_src[vs * 2 + h] + er, 0.f));
        den += ex;
        acc0 += ex * bflo(p);
        acc1 += ex * bfhi(p);
    }
    float inv = (den > 0.f) ? 1.f / den : 0.f;
    acc0 *= inv; acc1 *= inv;
    float b0 = __shfl_down(acc0, 32);
    float b1 = __shfl_down(acc1, 32);
    if (lane < 32) {
        int e0 = 2 * lane, e1 = 2 * lane + 1;
        float o0 = 0.5f * (acc0 + b0 + bias[e0] + bias[64 + e0]);
        float o1 = 0.5f * (acc1 + b1 + bias[e1] + bias[64 + e1]);
        reinterpret_cast<float2*>(out + (size_t)m * 64)[lane] = make_float2(o0, o1);
    }
}

extern "C" void kernel_launch(void* const* d_in, const int* in_sizes, int n_in,
                              void* d_out, int out_size, void* d_ws, size_t ws_size,
                              hipStream_t stream) {
    const float* vfeat   = (const float*)d_in[0];
    const float* efeat   = (const float*)d_in[1];
    const int*   inc_n   = (const int*)d_in[2];
    const int*   inc_h   = (const int*)d_in[3];
    const float* W_ke    = (const float*)d_in[4];
    const float* W_qe    = (const float*)d_in[5];
    const float* attn_ke = (const float*)d_in[6];
    const float* attn_qe = (const float*)d_in[7];
    const float* bias_e  = (const float*)d_in[8];
    const float* W_kv    = (const float*)d_in[9];
    const float* W_qv    = (const float*)d_in[10];
    const float* attn_kv = (const float*)d_in[11];
    const float* attn_qv = (const float*)d_in[12];
    const float* bias_v  = (const float*)d_in[13];

    float* ws = (float*)d_ws;
    unsigned int*   vke = (unsigned int*)(ws + OFF_VKE);
    unsigned int*   ekv = (unsigned int*)(ws + OFF_EKV);
    float* el   = ws + OFF_EL;
    float* er   = ws + OFF_ER;
    float* el2  = ws + OFF_EL2;
    float* er2  = ws + OFF_ER2;
    float* cqe  = ws + OFF_CQE;
    float* cqv  = ws + OFF_CQV;
    unsigned short* Wt = (unsigned short*)(ws + OFF_WT);
    int*   ib     = (int*)(ws + OFF_INT);
    int*   cnt    = ib + I_CNT;
    int*   offs   = ib + I_OFFS;
    int*   bsum   = ib + I_BSUM;
    int*   bscan  = ib + I_BSCAN;
    int*   csr    = ib + I_CSR;

    float* out_v = (float*)d_out;                   // [50000, 64]
    float* out_e = (float*)d_out + (size_t)NN * 64; // [10000, 64]

    // ---- CSR build (combined hedge+node segments) ----
    hipMemsetAsync(cnt, 0, (size_t)NTOT * sizeof(int), stream);
    hist_kernel<<<dim3((NE + 255) / 256), dim3(256), 0, stream>>>(inc_n, inc_h, cnt, NE);
    block_reduce_kernel<<<dim3(NBLK), dim3(SCAN_BS), 0, stream>>>(cnt, bsum, NTOT);
    scan_bsums_kernel<<<dim3(1), dim3(64), 0, stream>>>(bsum, bscan, NBLK, offs, NTOT);
    block_scan_kernel<<<dim3(NBLK), dim3(SCAN_BS), 0, stream>>>(cnt, bscan, offs, NTOT);
    hipMemsetAsync(cnt, 0, (size_t)NTOT * sizeof(int), stream);  // reuse as cursors
    csr_fill_kernel<<<dim3((NE + 255) / 256), dim3(256), 0, stream>>>(
        inc_n, inc_h, offs, cnt, csr, NE);

    // ---- attn folds + W conversion ----
    fold_attn_kernel<<<dim3(2), dim3(256), 0, stream>>>(W_qe, attn_qe, cqe, W_qv, attn_qv, cqv);
    convW_kernel<<<dim3(128), dim3(128), 0, stream>>>(W_ke, Wt);

    // ---- Phase 1: nodes -> hyperedges ----
    rows_dot_c_kernel<<<dim3((NM + 3) / 4), dim3(256), 0, stream>>>(efeat, cqe, er, NM);
    mfma_gemm128_kernel<<<dim3((NN + 63) / 64), dim3(256), 0, stream>>>(
        vfeat, Wt, attn_ke, cqv, (unsigned short*)vke, el, er2, NN);
    gather_kernel<<<dim3((NM + 3) / 4), dim3(256), 0, stream>>>(
        offs, csr, vke, el, er, bias_e, out_e, NM);

    // ---- Phase 2: hyperedges -> nodes ----
    gemm64_el_kernel<4><<<dim3((NM + 3) / 4), dim3(128), 0, stream>>>(
        out_e, W_kv, attn_kv, (unsigned short*)ekv, el2, NM);
    gather_kernel<<<dim3((NN + 3) / 4), dim3(256), 0, stream>>>(
        offs + NM, csr, ekv, el2, er2, bias_v, out_v, NN);
}

// Round 6
// 186.239 us; speedup vs baseline: 3.1990x; 1.2907x over previous
//
#include <hip/hip_runtime.h>
#include <hip/hip_bf16.h>

#define NN 50000      // nodes
#define NM 10000      // hyperedges
#define NE 500000     // incidences
#define NTOT (NM + NN)          // 60000 combined segments (hedges first)
#define SCAN_BS 1024
#define NBLK ((NTOT + SCAN_BS - 1) / SCAN_BS)   // 59

typedef short bf16x8 __attribute__((ext_vector_type(8)));
typedef unsigned short u16x8 __attribute__((ext_vector_type(8)));
typedef float f32x4 __attribute__((ext_vector_type(4)));

// ---------------- workspace layout ----------------
// float-sized slots:
//   vke(bf16 u32x64/row) 3,200,000 @ 0
//   ekv(bf16 u32x64/row)   640,000 @ 3,200,000
//   el      100,000 @ 3,840,000
//   er       20,000 @ 3,940,000
//   el2      20,000 @ 3,960,000
//   er2     100,000 @ 3,980,000
//   cqe         256 @ 4,080,000
//   cqv         256 @ 4,080,256
//   Wt (bf16 16384)  8,192 float slots @ 4,080,512
// ints (base = float offset 4,089,000):
//   cnt      60,000 @ 0
//   offs     60,001 @ 60,000
//   bsum         64 @ 120,001
//   bscan        64 @ 120,065
//   csr16  1,000,000 u16 = 500,000 int slots @ 120,129
//   rankh16  500,000 u16 = 250,000 int slots @ 620,129
//   rankn16  500,000 u16 = 250,000 int slots @ 870,129
static const size_t OFF_VKE  = 0;
static const size_t OFF_EKV  = 3200000;
static const size_t OFF_EL   = 3840000;
static const size_t OFF_ER   = 3940000;
static const size_t OFF_EL2  = 3960000;
static const size_t OFF_ER2  = 3980000;
static const size_t OFF_CQE  = 4080000;
static const size_t OFF_CQV  = 4080256;
static const size_t OFF_WT   = 4080512;
static const size_t OFF_INT  = 4089000;
static const size_t I_CNT    = 0;
static const size_t I_OFFS   = 60000;
static const size_t I_BSUM   = 120001;
static const size_t I_BSCAN  = 120065;
static const size_t I_CSR16  = 120129;
static const size_t I_RANKH  = 620129;
static const size_t I_RANKN  = 870129;

__device__ __forceinline__ unsigned short f2bf(float f) {
    unsigned int u = __float_as_uint(f);
    unsigned int r = (u + 0x7fffu + ((u >> 16) & 1u)) >> 16;   // RNE
    return (unsigned short)r;
}
__device__ __forceinline__ float bflo(unsigned int p) { return __uint_as_float(p << 16); }
__device__ __forceinline__ float bfhi(unsigned int p) { return __uint_as_float(p & 0xffff0000u); }

// ---- W [128 in][128 out] f32 -> Wt [out][in] bf16 ----
__global__ void convW_kernel(const float* __restrict__ W, unsigned short* __restrict__ Wt) {
    int col = blockIdx.x, k = threadIdx.x;           // 128 blocks x 128 threads
    Wt[col * 128 + k] = f2bf(W[k * 128 + col]);
}

// ---- MFMA GEMM: X[R,128]f32 @ Wt^T -> Y[R,128]bf16, + el (Y.attn) + er2 (X.cq) ----
__global__ void mfma_gemm128_kernel(const float* __restrict__ X,
                                    const unsigned short* __restrict__ Wt,
                                    const float* __restrict__ attn,
                                    const float* __restrict__ cq,
                                    unsigned short* __restrict__ Y,
                                    float* __restrict__ el,
                                    float* __restrict__ er2, int R) {
    __shared__ unsigned short Abuf[64 * 128];    // 16 KB, idx ^ ((row&7)<<3)
    __shared__ unsigned short Wbuf[128 * 128];   // 32 KB, idx ^ ((col&7)<<3)
    int tid = threadIdx.x;
    int m0 = blockIdx.x * 64;

    // ---- stage W (bf16 global, coalesced) ----
    {
        const u16x8* Wg = reinterpret_cast<const u16x8*>(Wt);
        #pragma unroll
        for (int i = 0; i < 8; ++i) {
            int idx16 = i * 256 + tid;           // 2048 x 16B
            u16x8 w8 = Wg[idx16];
            int col = idx16 >> 4, kb = idx16 & 15;
            int us = (col * 128 + kb * 8) ^ ((col & 7) << 3);
            *reinterpret_cast<u16x8*>(&Wbuf[us]) = w8;
        }
    }
    // ---- stage X (f32 -> bf16) + er2 partial dot with cq ----
    {
        int r = tid >> 2, q = tid & 3;           // 4 threads per row, 32 cols each
        int m = m0 + r;
        float p0 = 0.f, p1 = 0.f;
        if (m < R) {
            const float4* Xr = reinterpret_cast<const float4*>(X + (size_t)m * 128 + q * 32);
            #pragma unroll
            for (int i2 = 0; i2 < 4; ++i2) {
                float4 u = Xr[i2 * 2], v = Xr[i2 * 2 + 1];
                int k0 = q * 32 + i2 * 8;
                u16x8 w8;
                w8[0] = f2bf(u.x); w8[1] = f2bf(u.y); w8[2] = f2bf(u.z); w8[3] = f2bf(u.w);
                w8[4] = f2bf(v.x); w8[5] = f2bf(v.y); w8[6] = f2bf(v.z); w8[7] = f2bf(v.w);
                int us = (r * 128 + k0) ^ ((r & 7) << 3);
                *reinterpret_cast<u16x8*>(&Abuf[us]) = w8;
                p0 += u.x * cq[k0] + u.y * cq[k0 + 1] + u.z * cq[k0 + 2] + u.w * cq[k0 + 3]
                    + v.x * cq[k0 + 4] + v.y * cq[k0 + 5] + v.z * cq[k0 + 6] + v.w * cq[k0 + 7];
                p1 += u.x * cq[128 + k0] + u.y * cq[128 + k0 + 1] + u.z * cq[128 + k0 + 2] + u.w * cq[128 + k0 + 3]
                    + v.x * cq[128 + k0 + 4] + v.y * cq[128 + k0 + 5] + v.z * cq[128 + k0 + 6] + v.w * cq[128 + k0 + 7];
            }
        } else {
            u16x8 z = {0, 0, 0, 0, 0, 0, 0, 0};
            #pragma unroll
            for (int i2 = 0; i2 < 4; ++i2) {
                int us = (r * 128 + q * 32 + i2 * 8) ^ ((r & 7) << 3);
                *reinterpret_cast<u16x8*>(&Abuf[us]) = z;
            }
        }
        p0 += __shfl_xor(p0, 1); p0 += __shfl_xor(p0, 2);
        p1 += __shfl_xor(p1, 1); p1 += __shfl_xor(p1, 2);
        if (q == 0 && m < R)
            reinterpret_cast<float2*>(er2 + (size_t)m * 2)[0] = make_float2(p0, p1);
    }
    __syncthreads();

    // ---- MFMA: wave w -> rows [w*16, w*16+16), 8 col-tiles, 4 K-steps ----
    int l = tid & 63, w = tid >> 6;
    int lrow = w * 16 + (l & 15);
    f32x4 acc[8];
    #pragma unroll
    for (int ct = 0; ct < 8; ++ct) acc[ct] = (f32x4){0.f, 0.f, 0.f, 0.f};
    #pragma unroll
    for (int s = 0; s < 4; ++s) {
        int aidx = (lrow * 128 + s * 32 + (l >> 4) * 8) ^ ((lrow & 7) << 3);
        bf16x8 af = *reinterpret_cast<const bf16x8*>(&Abuf[aidx]);
        #pragma unroll
        for (int ct = 0; ct < 8; ++ct) {
            int col = ct * 16 + (l & 15);
            int bidx = (col * 128 + s * 32 + (l >> 4) * 8) ^ ((col & 7) << 3);
            bf16x8 bf = *reinterpret_cast<const bf16x8*>(&Wbuf[bidx]);
            acc[ct] = __builtin_amdgcn_mfma_f32_16x16x32_bf16(af, bf, acc[ct], 0, 0, 0);
        }
    }

    // ---- epilogue: Y bf16 store, el reduce ----
    float av[8];
    #pragma unroll
    for (int ct = 0; ct < 8; ++ct) av[ct] = attn[ct * 16 + (l & 15)];
    #pragma unroll
    for (int r = 0; r < 4; ++r) {
        int m = m0 + w * 16 + (l >> 4) * 4 + r;
        bool ok = (m < R);
        #pragma unroll
        for (int ct = 0; ct < 8; ++ct)
            if (ok) Y[(size_t)m * 128 + ct * 16 + (l & 15)] = f2bf(acc[ct][r]);
        #pragma unroll
        for (int h = 0; h < 2; ++h) {
            float p = acc[h * 4][r] * av[h * 4] + acc[h * 4 + 1][r] * av[h * 4 + 1]
                    + acc[h * 4 + 2][r] * av[h * 4 + 2] + acc[h * 4 + 3][r] * av[h * 4 + 3];
            p += __shfl_xor(p, 1); p += __shfl_xor(p, 2);
            p += __shfl_xor(p, 4); p += __shfl_xor(p, 8);
            if ((l & 15) == 0 && ok) el[(size_t)m * 2 + h] = p;
        }
    }
}

// ---- GEMM [R,64] @ [64,128] -> Ybf16 [R,128], plus el reduce ----
template<int RPB>
__global__ void gemm64_el_kernel(const float* __restrict__ X, const float* __restrict__ W,
                                 const float* __restrict__ attn, unsigned short* __restrict__ Y,
                                 float* __restrict__ el, int R) {
    __shared__ float rows[RPB][64];
    int tid = threadIdx.x;              // 0..127
    int r0 = blockIdx.x * RPB;
    for (int i = tid; i < RPB * 64; i += 128) {
        int r = i >> 6, k = i & 63;
        int m = r0 + r;
        rows[r][k] = (m < R) ? X[(size_t)m * 64 + k] : 0.f;
    }
    __syncthreads();
    float acc[RPB];
    #pragma unroll
    for (int r = 0; r < RPB; ++r) acc[r] = 0.f;
    #pragma unroll 8
    for (int k = 0; k < 64; ++k) {
        float wv = W[k * 128 + tid];
        #pragma unroll
        for (int r = 0; r < RPB; ++r) acc[r] += rows[r][k] * wv;
    }
    float av = attn[tid];
    int h = tid >> 6;
    for (int r = 0; r < RPB; ++r) {
        int m = r0 + r;
        if (m < R) Y[(size_t)m * 128 + tid] = f2bf(acc[r]);
        float v = acc[r] * av;
        for (int off = 32; off > 0; off >>= 1) v += __shfl_down(v, off);
        if ((tid & 63) == 0 && m < R) el[m * 2 + h] = v;
    }
}

// ---- both attn folds in one launch ----
__global__ void fold_attn_kernel(const float* __restrict__ Wa, const float* __restrict__ aa,
                                 float* __restrict__ ca,
                                 const float* __restrict__ Wb, const float* __restrict__ ab,
                                 float* __restrict__ cb) {
    const float* W    = blockIdx.x ? Wb : Wa;
    const float* attn = blockIdx.x ? ab : aa;
    float*       c    = blockIdx.x ? cb : ca;
    int t = threadIdx.x;                 // 0..255
    int h = t >> 7, k = t & 127;
    float s = 0.f;
    #pragma unroll 8
    for (int j = 0; j < 64; ++j) s += W[k * 128 + h * 64 + j] * attn[h * 64 + j];
    c[h * 128 + k] = s;
}

// ---- er[m][h] = X[m,:128] . c[h,:], one wave per row ----
__global__ void rows_dot_c_kernel(const float* __restrict__ X, const float* __restrict__ c,
                                  float* __restrict__ er, int R) {
    int tid = threadIdx.x;               // 0..255
    int wave = tid >> 6, lane = tid & 63;
    int m = blockIdx.x * 4 + wave;
    if (m >= R) return;
    float x0 = X[(size_t)m * 128 + lane];
    float x1 = X[(size_t)m * 128 + 64 + lane];
    float a0 = x0 * c[lane]       + x1 * c[64 + lane];
    float a1 = x0 * c[128 + lane] + x1 * c[192 + lane];
    for (int off = 32; off > 0; off >>= 1) {
        a0 += __shfl_down(a0, off);
        a1 += __shfl_down(a1, off);
    }
    if (lane == 0) { er[m * 2] = a0; er[m * 2 + 1] = a1; }
}

// ---- histogram + rank capture: rank = atomicAdd return ----
__global__ void hist_rank_kernel(const int* __restrict__ inc_n, const int* __restrict__ inc_h,
                                 int* __restrict__ cnt,
                                 unsigned short* __restrict__ rank_h,
                                 unsigned short* __restrict__ rank_n, int E) {
    int t = blockIdx.x * blockDim.x + threadIdx.x;
    if (t >= E) return;
    rank_h[t] = (unsigned short)atomicAdd(&cnt[inc_h[t]], 1);
    rank_n[t] = (unsigned short)atomicAdd(&cnt[NM + inc_n[t]], 1);
}

// ---- hierarchical exclusive scan ----
__global__ void block_reduce_kernel(const int* __restrict__ cnt, int* __restrict__ bsum, int n) {
    __shared__ int wsum[16];
    int tid = threadIdx.x;
    int i = blockIdx.x * SCAN_BS + tid;
    int v = (i < n) ? cnt[i] : 0;
    for (int off = 32; off > 0; off >>= 1) v += __shfl_down(v, off);
    if ((tid & 63) == 0) wsum[tid >> 6] = v;
    __syncthreads();
    if (tid < 64) {
        int s = (tid < 16) ? wsum[tid] : 0;
        for (int off = 8; off > 0; off >>= 1) s += __shfl_down(s, off);
        if (tid == 0) bsum[blockIdx.x] = s;
    }
}

__global__ void scan_bsums_kernel(const int* __restrict__ bsum, int* __restrict__ bscan,
                                  int nb, int* __restrict__ offs, int n) {
    int lane = threadIdx.x;      // 64 threads
    int v = (lane < nb) ? bsum[lane] : 0;
    int incl = v;
    for (int d = 1; d < 64; d <<= 1) {
        int t = __shfl_up(incl, d);
        if (lane >= d) incl += t;
    }
    if (lane < nb) bscan[lane] = incl - v;
    if (lane == 63) offs[n] = incl;
}

__global__ void block_scan_kernel(const int* __restrict__ cnt, const int* __restrict__ bscan,
                                  int* __restrict__ offs, int n) {
    __shared__ int wsum[16];
    int tid = threadIdx.x;
    int i = blockIdx.x * SCAN_BS + tid;
    int lane = tid & 63, widx = tid >> 6;
    int v = (i < n) ? cnt[i] : 0;
    int incl = v;
    for (int d = 1; d < 64; d <<= 1) {
        int t = __shfl_up(incl, d);
        if (lane >= d) incl += t;
    }
    if (lane == 63) wsum[widx] = incl;
    __syncthreads();
    if (tid < 64) {
        int s = (tid < 16) ? wsum[tid] : 0;
        int si = s;
        for (int d = 1; d < 16; d <<= 1) {
            int t = __shfl_up(si, d);
            if (tid >= d) si += t;
        }
        if (tid < 16) wsum[tid] = si - s;
    }
    __syncthreads();
    if (i < n) offs[i] = bscan[blockIdx.x] + wsum[widx] + (incl - v);
}

// ---- fill combined u16 CSR (no atomics; ranks precomputed) ----
__global__ void csr_fill_kernel(const int* __restrict__ inc_n, const int* __restrict__ inc_h,
                                const unsigned short* __restrict__ rank_h,
                                const unsigned short* __restrict__ rank_n,
                                const int* __restrict__ offs,
                                unsigned short* __restrict__ csr, int E) {
    int t = blockIdx.x * blockDim.x + threadIdx.x;
    if (t >= E) return;
    int n = inc_n[t], hd = inc_h[t];
    csr[offs[hd] + rank_h[t]] = (unsigned short)n;
    csr[offs[NM + n] + rank_n[t]] = (unsigned short)hd;
}

// ---- fused gather: wave per dest row, bf16x2 lanes, softmax+agg+bias+head-mean ----
__global__ void gather_kernel(const int* __restrict__ offs, const unsigned short* __restrict__ csr,
                              const unsigned int* __restrict__ src32,  // [*,64] bf16x2
                              const float* __restrict__ el_src,        // [*,2]
                              const float* __restrict__ er_dst,        // [R,2]
                              const float* __restrict__ bias,          // [128]
                              float* __restrict__ out, int R) {
    int wave = threadIdx.x >> 6, lane = threadIdx.x & 63;
    int m = blockIdx.x * 4 + wave;
    if (m >= R) return;
    int h = lane >> 5;                  // lanes 0-31: head0 elems, 32-63: head1
    int beg = offs[m], end = offs[m + 1];
    float er = er_dst[m * 2 + h];
    float acc0 = 0.f, acc1 = 0.f, den = 0.f;
    int i = beg;
    for (; i + 1 < end; i += 2) {
        int vs0 = csr[i], vs1 = csr[i + 1];
        unsigned int p0 = src32[(size_t)vs0 * 64 + lane];
        unsigned int p1 = src32[(size_t)vs1 * 64 + lane];
        float e0 = el_src[vs0 * 2 + h];
        float e1 = el_src[vs1 * 2 + h];
        float ex0 = __expf(fmaxf(e0 + er, 0.f));
        float ex1 = __expf(fmaxf(e1 + er, 0.f));
        den += ex0 + ex1;
        acc0 += ex0 * bflo(p0) + ex1 * bflo(p1);
        acc1 += ex0 * bfhi(p0) + ex1 * bfhi(p1);
    }
    if (i < end) {
        int vs = csr[i];
        unsigned int p = src32[(size_t)vs * 64 + lane];
        float ex = __expf(fmaxf(el_src[vs * 2 + h] + er, 0.f));
        den += ex;
        acc0 += ex * bflo(p);
        acc1 += ex * bfhi(p);
    }
    float inv = (den > 0.f) ? 1.f / den : 0.f;
    acc0 *= inv; acc1 *= inv;
    float b0 = __shfl_down(acc0, 32);
    float b1 = __shfl_down(acc1, 32);
    if (lane < 32) {
        int e0 = 2 * lane, e1 = 2 * lane + 1;
        float o0 = 0.5f * (acc0 + b0 + bias[e0] + bias[64 + e0]);
        float o1 = 0.5f * (acc1 + b1 + bias[e1] + bias[64 + e1]);
        reinterpret_cast<float2*>(out + (size_t)m * 64)[lane] = make_float2(o0, o1);
    }
}

extern "C" void kernel_launch(void* const* d_in, const int* in_sizes, int n_in,
                              void* d_out, int out_size, void* d_ws, size_t ws_size,
                              hipStream_t stream) {
    const float* vfeat   = (const float*)d_in[0];
    const float* efeat   = (const float*)d_in[1];
    const int*   inc_n   = (const int*)d_in[2];
    const int*   inc_h   = (const int*)d_in[3];
    const float* W_ke    = (const float*)d_in[4];
    const float* W_qe    = (const float*)d_in[5];
    const float* attn_ke = (const float*)d_in[6];
    const float* attn_qe = (const float*)d_in[7];
    const float* bias_e  = (const float*)d_in[8];
    const float* W_kv    = (const float*)d_in[9];
    const float* W_qv    = (const float*)d_in[10];
    const float* attn_kv = (const float*)d_in[11];
    const float* attn_qv = (const float*)d_in[12];
    const float* bias_v  = (const float*)d_in[13];

    float* ws = (float*)d_ws;
    unsigned int*   vke = (unsigned int*)(ws + OFF_VKE);
    unsigned int*   ekv = (unsigned int*)(ws + OFF_EKV);
    float* el   = ws + OFF_EL;
    float* er   = ws + OFF_ER;
    float* el2  = ws + OFF_EL2;
    float* er2  = ws + OFF_ER2;
    float* cqe  = ws + OFF_CQE;
    float* cqv  = ws + OFF_CQV;
    unsigned short* Wt = (unsigned short*)(ws + OFF_WT);
    int*   ib     = (int*)(ws + OFF_INT);
    int*   cnt    = ib + I_CNT;
    int*   offs   = ib + I_OFFS;
    int*   bsum   = ib + I_BSUM;
    int*   bscan  = ib + I_BSCAN;
    unsigned short* csr    = (unsigned short*)(ib + I_CSR16);
    unsigned short* rank_h = (unsigned short*)(ib + I_RANKH);
    unsigned short* rank_n = (unsigned short*)(ib + I_RANKN);

    float* out_v = (float*)d_out;                   // [50000, 64]
    float* out_e = (float*)d_out + (size_t)NN * 64; // [10000, 64]

    // ---- CSR build (combined hedge+node segments) ----
    hipMemsetAsync(cnt, 0, (size_t)NTOT * sizeof(int), stream);
    hist_rank_kernel<<<dim3((NE + 255) / 256), dim3(256), 0, stream>>>(
        inc_n, inc_h, cnt, rank_h, rank_n, NE);
    block_reduce_kernel<<<dim3(NBLK), dim3(SCAN_BS), 0, stream>>>(cnt, bsum, NTOT);
    scan_bsums_kernel<<<dim3(1), dim3(64), 0, stream>>>(bsum, bscan, NBLK, offs, NTOT);
    block_scan_kernel<<<dim3(NBLK), dim3(SCAN_BS), 0, stream>>>(cnt, bscan, offs, NTOT);
    csr_fill_kernel<<<dim3((NE + 255) / 256), dim3(256), 0, stream>>>(
        inc_n, inc_h, rank_h, rank_n, offs, csr, NE);

    // ---- attn folds + W conversion ----
    fold_attn_kernel<<<dim3(2), dim3(256), 0, stream>>>(W_qe, attn_qe, cqe, W_qv, attn_qv, cqv);
    convW_kernel<<<dim3(128), dim3(128), 0, stream>>>(W_ke, Wt);

    // ---- Phase 1: nodes -> hyperedges ----
    rows_dot_c_kernel<<<dim3((NM + 3) / 4), dim3(256), 0, stream>>>(efeat, cqe, er, NM);
    mfma_gemm128_kernel<<<dim3((NN + 63) / 64), dim3(256), 0, stream>>>(
        vfeat, Wt, attn_ke, cqv, (unsigned short*)vke, el, er2, NN);
    gather_kernel<<<dim3((NM + 3) / 4), dim3(256), 0, stream>>>(
        offs, csr, vke, el, er, bias_e, out_e, NM);

    // ---- Phase 2: hyperedges -> nodes ----
    gemm64_el_kernel<4><<<dim3((NM + 3) / 4), dim3(128), 0, stream>>>(
        out_e, W_kv, attn_kv, (unsigned short*)ekv, el2, NM);
    gather_kernel<<<dim3((NN + 3) / 4), dim3(256), 0, stream>>>(
        offs + NM, csr, ekv, el2, er2, bias_v, out_v, NN);
}

// Round 7
// 175.761 us; speedup vs baseline: 3.3897x; 1.0596x over previous
//
#include <hip/hip_runtime.h>
#include <hip/hip_bf16.h>

#define NN 50000      // nodes
#define NM 10000      // hyperedges
#define NE 500000     // incidences
#define CAPH 128      // fixed bin capacity per hedge (mean 50, sd 7 -> 11 sd)
#define CAPN 32       // fixed bin capacity per node  (mean 10, sd 3.2 -> 7 sd)
#define SPCAP 4096    // spill safety list

typedef short bf16x8 __attribute__((ext_vector_type(8)));
typedef unsigned short u16x8 __attribute__((ext_vector_type(8)));
typedef float f32x4 __attribute__((ext_vector_type(4)));

// ---------------- workspace layout ----------------
// float-sized slots:
//   vke(bf16 u32x64/row) 3,200,000 @ 0
//   ekv(bf16 u32x64/row)   640,000 @ 3,200,000
//   el      100,000 @ 3,840,000
//   er       20,000 @ 3,940,000
//   el2      20,000 @ 3,960,000
//   er2     100,000 @ 3,980,000
//   cqe         256 @ 4,080,000
//   cqv         256 @ 4,080,256
//   Wt (bf16 16384)  8,192 float slots @ 4,080,512
// ints (base = float offset 4,089,000):
//   cur      60,000 @ 0   (hedge cursors then node cursors)
//   spc_h         1 @ 60,000
//   spc_n         1 @ 60,001
//   csrH  1,280,000 u16 = 640,000 int @ 60,004
//   csrN  1,600,000 u16 = 800,000 int @ 700,004
//   spill_h  4096 int2 = 8,192 int @ 1,500,004
//   spill_n  4096 int2 = 8,192 int @ 1,508,196
static const size_t OFF_VKE  = 0;
static const size_t OFF_EKV  = 3200000;
static const size_t OFF_EL   = 3840000;
static const size_t OFF_ER   = 3940000;
static const size_t OFF_EL2  = 3960000;
static const size_t OFF_ER2  = 3980000;
static const size_t OFF_CQE  = 4080000;
static const size_t OFF_CQV  = 4080256;
static const size_t OFF_WT   = 4080512;
static const size_t OFF_INT  = 4089000;
static const size_t I_CUR    = 0;
static const size_t I_SPCH   = 60000;
static const size_t I_SPCN   = 60001;
static const size_t I_CSRH   = 60004;
static const size_t I_CSRN   = 700004;
static const size_t I_SPH    = 1500004;
static const size_t I_SPN    = 1508196;

__device__ __forceinline__ unsigned short f2bf(float f) {
    unsigned int u = __float_as_uint(f);
    unsigned int r = (u + 0x7fffu + ((u >> 16) & 1u)) >> 16;   // RNE
    return (unsigned short)r;
}
__device__ __forceinline__ float bflo(unsigned int p) { return __uint_as_float(p << 16); }
__device__ __forceinline__ float bfhi(unsigned int p) { return __uint_as_float(p & 0xffff0000u); }

// ---- prep: blocks 0,1 = attn folds; blocks 2..65 = W_ke f32 -> Wt bf16 transpose ----
__global__ void prep_kernel(const float* __restrict__ W_qe, const float* __restrict__ attn_qe,
                            float* __restrict__ cqe,
                            const float* __restrict__ W_qv, const float* __restrict__ attn_qv,
                            float* __restrict__ cqv,
                            const float* __restrict__ W_ke, unsigned short* __restrict__ Wt) {
    int b = blockIdx.x, t = threadIdx.x;     // 256 threads
    if (b < 2) {
        const float* W    = b ? W_qv : W_qe;
        const float* attn = b ? attn_qv : attn_qe;
        float*       c    = b ? cqv : cqe;
        int h = t >> 7, k = t & 127;
        float s = 0.f;
        #pragma unroll 8
        for (int j = 0; j < 64; ++j) s += W[k * 128 + h * 64 + j] * attn[h * 64 + j];
        c[h * 128 + k] = s;
    } else {
        int col = (b - 2) * 2 + (t >> 7), k = t & 127;
        Wt[col * 128 + k] = f2bf(W_ke[k * 128 + col]);
    }
}

// ---- single-pass fixed-capacity binning (replaces hist+scan+fill) ----
__global__ void bin_fill_kernel(const int* __restrict__ inc_n, const int* __restrict__ inc_h,
                                int* __restrict__ cur,
                                unsigned short* __restrict__ csrH, unsigned short* __restrict__ csrN,
                                int* __restrict__ spc_h, int2* __restrict__ spill_h,
                                int* __restrict__ spc_n, int2* __restrict__ spill_n, int E) {
    int t = blockIdx.x * blockDim.x + threadIdx.x;
    if (t >= E) return;
    int n = inc_n[t], hd = inc_h[t];
    int rh = atomicAdd(&cur[hd], 1);
    if (rh < CAPH) csrH[hd * CAPH + rh] = (unsigned short)n;
    else { int s = atomicAdd(spc_h, 1); if (s < SPCAP) spill_h[s] = make_int2(hd, n); }
    int rn = atomicAdd(&cur[NM + n], 1);
    if (rn < CAPN) csrN[n * CAPN + rn] = (unsigned short)hd;
    else { int s = atomicAdd(spc_n, 1); if (s < SPCAP) spill_n[s] = make_int2(n, hd); }
}

// ---- MFMA GEMM: X[R,128]f32 @ Wt^T -> Y[R,128]bf16, + el (Y.attn) + er2 (X.cq) ----
__global__ void mfma_gemm128_kernel(const float* __restrict__ X,
                                    const unsigned short* __restrict__ Wt,
                                    const float* __restrict__ attn,
                                    const float* __restrict__ cq,
                                    unsigned short* __restrict__ Y,
                                    float* __restrict__ el,
                                    float* __restrict__ er2, int R) {
    __shared__ unsigned short Abuf[64 * 128];    // 16 KB, idx ^ ((row&7)<<3)
    __shared__ unsigned short Wbuf[128 * 128];   // 32 KB, idx ^ ((col&7)<<3)
    int tid = threadIdx.x;
    int m0 = blockIdx.x * 64;

    // ---- stage W (bf16 global, coalesced) ----
    {
        const u16x8* Wg = reinterpret_cast<const u16x8*>(Wt);
        #pragma unroll
        for (int i = 0; i < 8; ++i) {
            int idx16 = i * 256 + tid;           // 2048 x 16B
            u16x8 w8 = Wg[idx16];
            int col = idx16 >> 4, kb = idx16 & 15;
            int us = (col * 128 + kb * 8) ^ ((col & 7) << 3);
            *reinterpret_cast<u16x8*>(&Wbuf[us]) = w8;
        }
    }
    // ---- stage X (f32 -> bf16) + er2 partial dot with cq ----
    {
        int r = tid >> 2, q = tid & 3;           // 4 threads per row, 32 cols each
        int m = m0 + r;
        float p0 = 0.f, p1 = 0.f;
        if (m < R) {
            const float4* Xr = reinterpret_cast<const float4*>(X + (size_t)m * 128 + q * 32);
            #pragma unroll
            for (int i2 = 0; i2 < 4; ++i2) {
                float4 u = Xr[i2 * 2], v = Xr[i2 * 2 + 1];
                int k0 = q * 32 + i2 * 8;
                u16x8 w8;
                w8[0] = f2bf(u.x); w8[1] = f2bf(u.y); w8[2] = f2bf(u.z); w8[3] = f2bf(u.w);
                w8[4] = f2bf(v.x); w8[5] = f2bf(v.y); w8[6] = f2bf(v.z); w8[7] = f2bf(v.w);
                int us = (r * 128 + k0) ^ ((r & 7) << 3);
                *reinterpret_cast<u16x8*>(&Abuf[us]) = w8;
                p0 += u.x * cq[k0] + u.y * cq[k0 + 1] + u.z * cq[k0 + 2] + u.w * cq[k0 + 3]
                    + v.x * cq[k0 + 4] + v.y * cq[k0 + 5] + v.z * cq[k0 + 6] + v.w * cq[k0 + 7];
                p1 += u.x * cq[128 + k0] + u.y * cq[128 + k0 + 1] + u.z * cq[128 + k0 + 2] + u.w * cq[128 + k0 + 3]
                    + v.x * cq[128 + k0 + 4] + v.y * cq[128 + k0 + 5] + v.z * cq[128 + k0 + 6] + v.w * cq[128 + k0 + 7];
            }
        } else {
            u16x8 z = {0, 0, 0, 0, 0, 0, 0, 0};
            #pragma unroll
            for (int i2 = 0; i2 < 4; ++i2) {
                int us = (r * 128 + q * 32 + i2 * 8) ^ ((r & 7) << 3);
                *reinterpret_cast<u16x8*>(&Abuf[us]) = z;
            }
        }
        p0 += __shfl_xor(p0, 1); p0 += __shfl_xor(p0, 2);
        p1 += __shfl_xor(p1, 1); p1 += __shfl_xor(p1, 2);
        if (q == 0 && m < R)
            reinterpret_cast<float2*>(er2 + (size_t)m * 2)[0] = make_float2(p0, p1);
    }
    __syncthreads();

    // ---- MFMA: wave w -> rows [w*16, w*16+16), 8 col-tiles, 4 K-steps ----
    int l = tid & 63, w = tid >> 6;
    int lrow = w * 16 + (l & 15);
    f32x4 acc[8];
    #pragma unroll
    for (int ct = 0; ct < 8; ++ct) acc[ct] = (f32x4){0.f, 0.f, 0.f, 0.f};
    #pragma unroll
    for (int s = 0; s < 4; ++s) {
        int aidx = (lrow * 128 + s * 32 + (l >> 4) * 8) ^ ((lrow & 7) << 3);
        bf16x8 af = *reinterpret_cast<const bf16x8*>(&Abuf[aidx]);
        #pragma unroll
        for (int ct = 0; ct < 8; ++ct) {
            int col = ct * 16 + (l & 15);
            int bidx = (col * 128 + s * 32 + (l >> 4) * 8) ^ ((col & 7) << 3);
            bf16x8 bf = *reinterpret_cast<const bf16x8*>(&Wbuf[bidx]);
            acc[ct] = __builtin_amdgcn_mfma_f32_16x16x32_bf16(af, bf, acc[ct], 0, 0, 0);
        }
    }

    // ---- epilogue: Y bf16 store, el reduce ----
    float av[8];
    #pragma unroll
    for (int ct = 0; ct < 8; ++ct) av[ct] = attn[ct * 16 + (l & 15)];
    #pragma unroll
    for (int r = 0; r < 4; ++r) {
        int m = m0 + w * 16 + (l >> 4) * 4 + r;
        bool ok = (m < R);
        #pragma unroll
        for (int ct = 0; ct < 8; ++ct)
            if (ok) Y[(size_t)m * 128 + ct * 16 + (l & 15)] = f2bf(acc[ct][r]);
        #pragma unroll
        for (int h = 0; h < 2; ++h) {
            float p = acc[h * 4][r] * av[h * 4] + acc[h * 4 + 1][r] * av[h * 4 + 1]
                    + acc[h * 4 + 2][r] * av[h * 4 + 2] + acc[h * 4 + 3][r] * av[h * 4 + 3];
            p += __shfl_xor(p, 1); p += __shfl_xor(p, 2);
            p += __shfl_xor(p, 4); p += __shfl_xor(p, 8);
            if ((l & 15) == 0 && ok) el[(size_t)m * 2 + h] = p;
        }
    }
}

// ---- GEMM [R,64] @ [64,128] -> Ybf16 [R,128], plus el reduce ----
template<int RPB>
__global__ void gemm64_el_kernel(const float* __restrict__ X, const float* __restrict__ W,
                                 const float* __restrict__ attn, unsigned short* __restrict__ Y,
                                 float* __restrict__ el, int R) {
    __shared__ float rows[RPB][64];
    int tid = threadIdx.x;              // 0..127
    int r0 = blockIdx.x * RPB;
    for (int i = tid; i < RPB * 64; i += 128) {
        int r = i >> 6, k = i & 63;
        int m = r0 + r;
        rows[r][k] = (m < R) ? X[(size_t)m * 64 + k] : 0.f;
    }
    __syncthreads();
    float acc[RPB];
    #pragma unroll
    for (int r = 0; r < RPB; ++r) acc[r] = 0.f;
    #pragma unroll 8
    for (int k = 0; k < 64; ++k) {
        float wv = W[k * 128 + tid];
        #pragma unroll
        for (int r = 0; r < RPB; ++r) acc[r] += rows[r][k] * wv;
    }
    float av = attn[tid];
    int h = tid >> 6;
    for (int r = 0; r < RPB; ++r) {
        int m = r0 + r;
        if (m < R) Y[(size_t)m * 128 + tid] = f2bf(acc[r]);
        float v = acc[r] * av;
        for (int off = 32; off > 0; off >>= 1) v += __shfl_down(v, off);
        if ((tid & 63) == 0 && m < R) el[m * 2 + h] = v;
    }
}

// ---- er[m][h] = X[m,:128] . c[h,:], one wave per row ----
__global__ void rows_dot_c_kernel(const float* __restrict__ X, const float* __restrict__ c,
                                  float* __restrict__ er, int R) {
    int tid = threadIdx.x;               // 0..255
    int wave = tid >> 6, lane = tid & 63;
    int m = blockIdx.x * 4 + wave;
    if (m >= R) return;
    float x0 = X[(size_t)m * 128 + lane];
    float x1 = X[(size_t)m * 128 + 64 + lane];
    float a0 = x0 * c[lane]       + x1 * c[64 + lane];
    float a1 = x0 * c[128 + lane] + x1 * c[192 + lane];
    for (int off = 32; off > 0; off >>= 1) {
        a0 += __shfl_down(a0, off);
        a1 += __shfl_down(a1, off);
    }
    if (lane == 0) { er[m * 2] = a0; er[m * 2 + 1] = a1; }
}

// ---- fused gather over fixed-cap bins: wave/dest, softmax+agg+bias+head-mean ----
template<int CAP>
__global__ void gather_kernel(const int* __restrict__ cnt, const unsigned short* __restrict__ csr,
                              const unsigned int* __restrict__ src32,  // [*,64] bf16x2
                              const float* __restrict__ el_src,        // [*,2]
                              const float* __restrict__ er_dst,        // [R,2]
                              const float* __restrict__ bias,          // [128]
                              const int* __restrict__ spc, const int2* __restrict__ spill,
                              float* __restrict__ out, int R) {
    int wave = threadIdx.x >> 6, lane = threadIdx.x & 63;
    int m = blockIdx.x * 4 + wave;
    if (m >= R) return;
    int h = lane >> 5;                  // lanes 0-31: head0 elems, 32-63: head1
    int c = cnt[m]; if (c > CAP) c = CAP;
    int beg = m * CAP, end = beg + c;
    float er = er_dst[m * 2 + h];
    float acc0 = 0.f, acc1 = 0.f, den = 0.f;
    int i = beg;
    for (; i + 1 < end; i += 2) {
        int vs0 = csr[i], vs1 = csr[i + 1];
        unsigned int p0 = src32[(size_t)vs0 * 64 + lane];
        unsigned int p1 = src32[(size_t)vs1 * 64 + lane];
        float e0 = el_src[vs0 * 2 + h];
        float e1 = el_src[vs1 * 2 + h];
        float ex0 = __expf(fmaxf(e0 + er, 0.f));
        float ex1 = __expf(fmaxf(e1 + er, 0.f));
        den += ex0 + ex1;
        acc0 += ex0 * bflo(p0) + ex1 * bflo(p1);
        acc1 += ex0 * bfhi(p0) + ex1 * bfhi(p1);
    }
    if (i < end) {
        int vs = csr[i];
        unsigned int p = src32[(size_t)vs * 64 + lane];
        float ex = __expf(fmaxf(el_src[vs * 2 + h] + er, 0.f));
        den += ex;
        acc0 += ex * bflo(p);
        acc1 += ex * bfhi(p);
    }
    // spill safety (expected empty: one broadcast load)
    int sc = *spc; if (sc > SPCAP) sc = SPCAP;
    for (int s = 0; s < sc; ++s) {
        int2 pr = spill[s];
        if (pr.x == m) {
            int vs = pr.y;
            unsigned int p = src32[(size_t)vs * 64 + lane];
            float ex = __expf(fmaxf(el_src[vs * 2 + h] + er, 0.f));
            den += ex;
            acc0 += ex * bflo(p);
            acc1 += ex * bfhi(p);
        }
    }
    float inv = (den > 0.f) ? 1.f / den : 0.f;
    acc0 *= inv; acc1 *= inv;
    float b0 = __shfl_down(acc0, 32);
    float b1 = __shfl_down(acc1, 32);
    if (lane < 32) {
        int e0 = 2 * lane, e1 = 2 * lane + 1;
        float o0 = 0.5f * (acc0 + b0 + bias[e0] + bias[64 + e0]);
        float o1 = 0.5f * (acc1 + b1 + bias[e1] + bias[64 + e1]);
        reinterpret_cast<float2*>(out + (size_t)m * 64)[lane] = make_float2(o0, o1);
    }
}

extern "C" void kernel_launch(void* const* d_in, const int* in_sizes, int n_in,
                              void* d_out, int out_size, void* d_ws, size_t ws_size,
                              hipStream_t stream) {
    const float* vfeat   = (const float*)d_in[0];
    const float* efeat   = (const float*)d_in[1];
    const int*   inc_n   = (const int*)d_in[2];
    const int*   inc_h   = (const int*)d_in[3];
    const float* W_ke    = (const float*)d_in[4];
    const float* W_qe    = (const float*)d_in[5];
    const float* attn_ke = (const float*)d_in[6];
    const float* attn_qe = (const float*)d_in[7];
    const float* bias_e  = (const float*)d_in[8];
    const float* W_kv    = (const float*)d_in[9];
    const float* W_qv    = (const float*)d_in[10];
    const float* attn_kv = (const float*)d_in[11];
    const float* attn_qv = (const float*)d_in[12];
    const float* bias_v  = (const float*)d_in[13];

    float* ws = (float*)d_ws;
    unsigned int*   vke = (unsigned int*)(ws + OFF_VKE);
    unsigned int*   ekv = (unsigned int*)(ws + OFF_EKV);
    float* el   = ws + OFF_EL;
    float* er   = ws + OFF_ER;
    float* el2  = ws + OFF_EL2;
    float* er2  = ws + OFF_ER2;
    float* cqe  = ws + OFF_CQE;
    float* cqv  = ws + OFF_CQV;
    unsigned short* Wt = (unsigned short*)(ws + OFF_WT);
    int*   ib      = (int*)(ws + OFF_INT);
    int*   cur     = ib + I_CUR;
    int*   spc_h   = ib + I_SPCH;
    int*   spc_n   = ib + I_SPCN;
    unsigned short* csrH = (unsigned short*)(ib + I_CSRH);
    unsigned short* csrN = (unsigned short*)(ib + I_CSRN);
    int2*  spill_h = (int2*)(ib + I_SPH);
    int2*  spill_n = (int2*)(ib + I_SPN);

    float* out_v = (float*)d_out;                   // [50000, 64]
    float* out_e = (float*)d_out + (size_t)NN * 64; // [10000, 64]

    // ---- zero cursors + spill counts (contiguous) ----
    hipMemsetAsync(cur, 0, (size_t)(NM + NN + 2) * sizeof(int), stream);

    // ---- prep (attn folds + W transpose) ----
    prep_kernel<<<dim3(66), dim3(256), 0, stream>>>(W_qe, attn_qe, cqe, W_qv, attn_qv, cqv,
                                                    W_ke, Wt);

    // ---- one-pass binning ----
    bin_fill_kernel<<<dim3((NE + 255) / 256), dim3(256), 0, stream>>>(
        inc_n, inc_h, cur, csrH, csrN, spc_h, spill_h, spc_n, spill_n, NE);

    // ---- Phase 1: nodes -> hyperedges ----
    rows_dot_c_kernel<<<dim3((NM + 3) / 4), dim3(256), 0, stream>>>(efeat, cqe, er, NM);
    mfma_gemm128_kernel<<<dim3((NN + 63) / 64), dim3(256), 0, stream>>>(
        vfeat, Wt, attn_ke, cqv, (unsigned short*)vke, el, er2, NN);
    gather_kernel<CAPH><<<dim3((NM + 3) / 4), dim3(256), 0, stream>>>(
        cur, csrH, vke, el, er, bias_e, spc_h, spill_h, out_e, NM);

    // ---- Phase 2: hyperedges -> nodes ----
    gemm64_el_kernel<4><<<dim3((NM + 3) / 4), dim3(128), 0, stream>>>(
        out_e, W_kv, attn_kv, (unsigned short*)ekv, el2, NM);
    gather_kernel<CAPN><<<dim3((NN + 3) / 4), dim3(256), 0, stream>>>(
        cur + NM, csrN, ekv, el2, er2, bias_v, spc_n, spill_n, out_v, NN);
}

// Round 8
// 148.771 us; speedup vs baseline: 4.0046x; 1.1814x over previous
//
#include <hip/hip_runtime.h>
#include <hip/hip_bf16.h>

#define NN 50000      // nodes
#define NM 10000      // hyperedges
#define NE 500000     // incidences
#define CAPH 128      // fixed bin capacity per hedge (mean 50, sd 7 -> 11 sd)
#define CAPN 32       // fixed bin capacity per node  (mean 10, sd 3.2 -> 7 sd)
#define SPCAP 4096    // spill safety list

// phase1 merged-kernel role partition
#define BIN_BLK   240
#define GEMM_TILES ((NN + 63) / 64)          // 782
#define ROWS_BLK  300
#define P1_GRID   (BIN_BLK + GEMM_TILES + ROWS_BLK)

typedef short bf16x8 __attribute__((ext_vector_type(8)));
typedef unsigned short u16x8 __attribute__((ext_vector_type(8)));
typedef float f32x4 __attribute__((ext_vector_type(4)));

// ---------------- workspace layout ----------------
// float-sized slots:
//   vke(bf16 u32x64/row) 3,200,000 @ 0
//   ekv(bf16 u32x64/row)   640,000 @ 3,200,000
//   el      100,000 @ 3,840,000
//   er       20,000 @ 3,940,000
//   el2      20,000 @ 3,960,000
//   er2     100,000 @ 3,980,000
//   cqe         256 @ 4,080,000
//   cqv         256 @ 4,080,256
//   Wt (bf16 16384)  8,192 float slots @ 4,080,512
// ints (base = float offset 4,089,000):
//   cur      60,000 @ 0   (hedge cursors then node cursors)
//   spc_h         1 @ 60,000
//   spc_n         1 @ 60,001
//   csrH  1,280,000 u16 = 640,000 int @ 60,004
//   csrN  1,600,000 u16 = 800,000 int @ 700,004
//   spill_h  4096 int2 = 8,192 int @ 1,500,004
//   spill_n  4096 int2 = 8,192 int @ 1,508,196
static const size_t OFF_VKE  = 0;
static const size_t OFF_EKV  = 3200000;
static const size_t OFF_EL   = 3840000;
static const size_t OFF_ER   = 3940000;
static const size_t OFF_EL2  = 3960000;
static const size_t OFF_ER2  = 3980000;
static const size_t OFF_CQE  = 4080000;
static const size_t OFF_CQV  = 4080256;
static const size_t OFF_WT   = 4080512;
static const size_t OFF_INT  = 4089000;
static const size_t I_CUR    = 0;
static const size_t I_SPCH   = 60000;
static const size_t I_SPCN   = 60001;
static const size_t I_CSRH   = 60004;
static const size_t I_CSRN   = 700004;
static const size_t I_SPH    = 1500004;
static const size_t I_SPN    = 1508196;

__device__ __forceinline__ unsigned short f2bf(float f) {
    unsigned int u = __float_as_uint(f);
    unsigned int r = (u + 0x7fffu + ((u >> 16) & 1u)) >> 16;   // RNE
    return (unsigned short)r;
}
__device__ __forceinline__ float bflo(unsigned int p) { return __uint_as_float(p << 16); }
__device__ __forceinline__ float bfhi(unsigned int p) { return __uint_as_float(p & 0xffff0000u); }

// ---- prep: zero cursors/spill counts; blocks 0,1 = attn folds; 2..65 = Wt transpose ----
__global__ void prep_kernel(const float* __restrict__ W_qe, const float* __restrict__ attn_qe,
                            float* __restrict__ cqe,
                            const float* __restrict__ W_qv, const float* __restrict__ attn_qv,
                            float* __restrict__ cqv,
                            const float* __restrict__ W_ke, unsigned short* __restrict__ Wt,
                            int* __restrict__ cur) {
    int b = blockIdx.x, t = threadIdx.x;     // 66 blocks x 256 threads
    for (int i = b * 256 + t; i < NM + NN + 2; i += 66 * 256) cur[i] = 0;
    if (b < 2) {
        const float* W    = b ? W_qv : W_qe;
        const float* attn = b ? attn_qv : attn_qe;
        float*       c    = b ? cqv : cqe;
        int h = t >> 7, k = t & 127;
        float s = 0.f;
        #pragma unroll 8
        for (int j = 0; j < 64; ++j) s += W[k * 128 + h * 64 + j] * attn[h * 64 + j];
        c[h * 128 + k] = s;
    } else {
        int col = (b - 2) * 2 + (t >> 7), k = t & 127;
        Wt[col * 128 + k] = f2bf(W_ke[k * 128 + col]);
    }
}

// ---- phase1 merged kernel: binning || MFMA GEMM+el+er2 || er rows ----
struct P1Smem {
    unsigned short Abuf[64 * 128];   // 16 KB
    unsigned short Wbuf[128 * 128];  // 32 KB
};

__global__ __launch_bounds__(256) void phase1_kernel(
        // bin role
        const int* __restrict__ inc_n, const int* __restrict__ inc_h,
        int* __restrict__ cur,
        unsigned short* __restrict__ csrH, unsigned short* __restrict__ csrN,
        int* __restrict__ spc_h, int2* __restrict__ spill_h,
        int* __restrict__ spc_n, int2* __restrict__ spill_n,
        // gemm role
        const float* __restrict__ X, const unsigned short* __restrict__ Wt,
        const float* __restrict__ attn, const float* __restrict__ cq,
        unsigned short* __restrict__ Y, float* __restrict__ el, float* __restrict__ er2,
        // rows_dot role
        const float* __restrict__ EF, const float* __restrict__ cqe,
        float* __restrict__ er) {
    __shared__ P1Smem sm;
    int bid = blockIdx.x, tid = threadIdx.x;

    if (bid < BIN_BLK) {
        // ================= binning (grid-strided over edges) =================
        for (int t = bid * 256 + tid; t < NE; t += BIN_BLK * 256) {
            int n = inc_n[t], hd = inc_h[t];
            int rh = atomicAdd(&cur[hd], 1);
            if (rh < CAPH) csrH[hd * CAPH + rh] = (unsigned short)n;
            else { int s = atomicAdd(spc_h, 1); if (s < SPCAP) spill_h[s] = make_int2(hd, n); }
            int rn = atomicAdd(&cur[NM + n], 1);
            if (rn < CAPN) csrN[n * CAPN + rn] = (unsigned short)hd;
            else { int s = atomicAdd(spc_n, 1); if (s < SPCAP) spill_n[s] = make_int2(n, hd); }
        }
        return;
    }
    if (bid >= BIN_BLK + GEMM_TILES) {
        // ================= er rows: er[m][h] = EF[m,:].cqe[h,:] =================
        int wave = tid >> 6, lane = tid & 63;
        for (int g = bid - BIN_BLK - GEMM_TILES; g < (NM + 3) / 4; g += ROWS_BLK) {
            int m = g * 4 + wave;
            if (m < NM) {
                float x0 = EF[(size_t)m * 128 + lane];
                float x1 = EF[(size_t)m * 128 + 64 + lane];
                float a0 = x0 * cqe[lane]       + x1 * cqe[64 + lane];
                float a1 = x0 * cqe[128 + lane] + x1 * cqe[192 + lane];
                for (int off = 32; off > 0; off >>= 1) {
                    a0 += __shfl_down(a0, off);
                    a1 += __shfl_down(a1, off);
                }
                if (lane == 0) { er[m * 2] = a0; er[m * 2 + 1] = a1; }
            }
        }
        return;
    }

    // ================= MFMA GEMM tile =================
    int m0 = (bid - BIN_BLK) * 64;
    const int R = NN;
    // ---- stage W (bf16 global, coalesced) ----
    {
        const u16x8* Wg = reinterpret_cast<const u16x8*>(Wt);
        #pragma unroll
        for (int i = 0; i < 8; ++i) {
            int idx16 = i * 256 + tid;           // 2048 x 16B
            u16x8 w8 = Wg[idx16];
            int col = idx16 >> 4, kb = idx16 & 15;
            int us = (col * 128 + kb * 8) ^ ((col & 7) << 3);
            *reinterpret_cast<u16x8*>(&sm.Wbuf[us]) = w8;
        }
    }
    // ---- stage X (f32 -> bf16) + er2 partial dot with cq ----
    {
        int r = tid >> 2, q = tid & 3;           // 4 threads per row, 32 cols each
        int m = m0 + r;
        float p0 = 0.f, p1 = 0.f;
        if (m < R) {
            const float4* Xr = reinterpret_cast<const float4*>(X + (size_t)m * 128 + q * 32);
            #pragma unroll
            for (int i2 = 0; i2 < 4; ++i2) {
                float4 u = Xr[i2 * 2], v = Xr[i2 * 2 + 1];
                int k0 = q * 32 + i2 * 8;
                u16x8 w8;
                w8[0] = f2bf(u.x); w8[1] = f2bf(u.y); w8[2] = f2bf(u.z); w8[3] = f2bf(u.w);
                w8[4] = f2bf(v.x); w8[5] = f2bf(v.y); w8[6] = f2bf(v.z); w8[7] = f2bf(v.w);
                int us = (r * 128 + k0) ^ ((r & 7) << 3);
                *reinterpret_cast<u16x8*>(&sm.Abuf[us]) = w8;
                p0 += u.x * cq[k0] + u.y * cq[k0 + 1] + u.z * cq[k0 + 2] + u.w * cq[k0 + 3]
                    + v.x * cq[k0 + 4] + v.y * cq[k0 + 5] + v.z * cq[k0 + 6] + v.w * cq[k0 + 7];
                p1 += u.x * cq[128 + k0] + u.y * cq[128 + k0 + 1] + u.z * cq[128 + k0 + 2] + u.w * cq[128 + k0 + 3]
                    + v.x * cq[128 + k0 + 4] + v.y * cq[128 + k0 + 5] + v.z * cq[128 + k0 + 6] + v.w * cq[128 + k0 + 7];
            }
        } else {
            u16x8 z = {0, 0, 0, 0, 0, 0, 0, 0};
            #pragma unroll
            for (int i2 = 0; i2 < 4; ++i2) {
                int us = (r * 128 + q * 32 + i2 * 8) ^ ((r & 7) << 3);
                *reinterpret_cast<u16x8*>(&sm.Abuf[us]) = z;
            }
        }
        p0 += __shfl_xor(p0, 1); p0 += __shfl_xor(p0, 2);
        p1 += __shfl_xor(p1, 1); p1 += __shfl_xor(p1, 2);
        if (q == 0 && m < R)
            reinterpret_cast<float2*>(er2 + (size_t)m * 2)[0] = make_float2(p0, p1);
    }
    __syncthreads();

    // ---- MFMA: wave w -> rows [w*16, w*16+16), 8 col-tiles, 4 K-steps ----
    int l = tid & 63, w = tid >> 6;
    int lrow = w * 16 + (l & 15);
    f32x4 acc[8];
    #pragma unroll
    for (int ct = 0; ct < 8; ++ct) acc[ct] = (f32x4){0.f, 0.f, 0.f, 0.f};
    #pragma unroll
    for (int s = 0; s < 4; ++s) {
        int aidx = (lrow * 128 + s * 32 + (l >> 4) * 8) ^ ((lrow & 7) << 3);
        bf16x8 af = *reinterpret_cast<const bf16x8*>(&sm.Abuf[aidx]);
        #pragma unroll
        for (int ct = 0; ct < 8; ++ct) {
            int col = ct * 16 + (l & 15);
            int bidx = (col * 128 + s * 32 + (l >> 4) * 8) ^ ((col & 7) << 3);
            bf16x8 bf = *reinterpret_cast<const bf16x8*>(&sm.Wbuf[bidx]);
            acc[ct] = __builtin_amdgcn_mfma_f32_16x16x32_bf16(af, bf, acc[ct], 0, 0, 0);
        }
    }

    // ---- epilogue: Y bf16 store, el reduce ----
    float av[8];
    #pragma unroll
    for (int ct = 0; ct < 8; ++ct) av[ct] = attn[ct * 16 + (l & 15)];
    #pragma unroll
    for (int r = 0; r < 4; ++r) {
        int m = m0 + w * 16 + (l >> 4) * 4 + r;
        bool ok = (m < R);
        #pragma unroll
        for (int ct = 0; ct < 8; ++ct)
            if (ok) Y[(size_t)m * 128 + ct * 16 + (l & 15)] = f2bf(acc[ct][r]);
        #pragma unroll
        for (int h = 0; h < 2; ++h) {
            float p = acc[h * 4][r] * av[h * 4] + acc[h * 4 + 1][r] * av[h * 4 + 1]
                    + acc[h * 4 + 2][r] * av[h * 4 + 2] + acc[h * 4 + 3][r] * av[h * 4 + 3];
            p += __shfl_xor(p, 1); p += __shfl_xor(p, 2);
            p += __shfl_xor(p, 4); p += __shfl_xor(p, 8);
            if ((l & 15) == 0 && ok) el[(size_t)m * 2 + h] = p;
        }
    }
}

// ---- GEMM [R,64] @ [64,128] -> Ybf16 [R,128], plus el reduce ----
template<int RPB>
__global__ void gemm64_el_kernel(const float* __restrict__ X, const float* __restrict__ W,
                                 const float* __restrict__ attn, unsigned short* __restrict__ Y,
                                 float* __restrict__ el, int R) {
    __shared__ float rows[RPB][64];
    int tid = threadIdx.x;              // 0..127
    int r0 = blockIdx.x * RPB;
    for (int i = tid; i < RPB * 64; i += 128) {
        int r = i >> 6, k = i & 63;
        int m = r0 + r;
        rows[r][k] = (m < R) ? X[(size_t)m * 64 + k] : 0.f;
    }
    __syncthreads();
    float acc[RPB];
    #pragma unroll
    for (int r = 0; r < RPB; ++r) acc[r] = 0.f;
    #pragma unroll 8
    for (int k = 0; k < 64; ++k) {
        float wv = W[k * 128 + tid];
        #pragma unroll
        for (int r = 0; r < RPB; ++r) acc[r] += rows[r][k] * wv;
    }
    float av = attn[tid];
    int h = tid >> 6;
    for (int r = 0; r < RPB; ++r) {
        int m = r0 + r;
        if (m < R) Y[(size_t)m * 128 + tid] = f2bf(acc[r]);
        float v = acc[r] * av;
        for (int off = 32; off > 0; off >>= 1) v += __shfl_down(v, off);
        if ((tid & 63) == 0 && m < R) el[m * 2 + h] = v;
    }
}

// ---- fused gather over fixed-cap bins: wave/dest, softmax+agg+bias+head-mean ----
template<int CAP>
__global__ void gather_kernel(const int* __restrict__ cnt, const unsigned short* __restrict__ csr,
                              const unsigned int* __restrict__ src32,  // [*,64] bf16x2
                              const float* __restrict__ el_src,        // [*,2]
                              const float* __restrict__ er_dst,        // [R,2]
                              const float* __restrict__ bias,          // [128]
                              const int* __restrict__ spc, const int2* __restrict__ spill,
                              float* __restrict__ out, int R) {
    int wave = threadIdx.x >> 6, lane = threadIdx.x & 63;
    int m = blockIdx.x * 4 + wave;
    if (m >= R) return;
    int h = lane >> 5;                  // lanes 0-31: head0 elems, 32-63: head1
    int c = cnt[m]; if (c > CAP) c = CAP;
    int beg = m * CAP, end = beg + c;
    float er = er_dst[m * 2 + h];
    float acc0 = 0.f, acc1 = 0.f, den = 0.f;
    int i = beg;
    for (; i + 1 < end; i += 2) {
        int vs0 = csr[i], vs1 = csr[i + 1];
        unsigned int p0 = src32[(size_t)vs0 * 64 + lane];
        unsigned int p1 = src32[(size_t)vs1 * 64 + lane];
        float e0 = el_src[vs0 * 2 + h];
        float e1 = el_src[vs1 * 2 + h];
        float ex0 = __expf(fmaxf(e0 + er, 0.f));
        float ex1 = __expf(fmaxf(e1 + er, 0.f));
        den += ex0 + ex1;
        acc0 += ex0 * bflo(p0) + ex1 * bflo(p1);
        acc1 += ex0 * bfhi(p0) + ex1 * bfhi(p1);
    }
    if (i < end) {
        int vs = csr[i];
        unsigned int p = src32[(size_t)vs * 64 + lane];
        float ex = __expf(fmaxf(el_src[vs * 2 + h] + er, 0.f));
        den += ex;
        acc0 += ex * bflo(p);
        acc1 += ex * bfhi(p);
    }
    // spill safety (expected empty: one broadcast load)
    int sc = *spc; if (sc > SPCAP) sc = SPCAP;
    for (int s = 0; s < sc; ++s) {
        int2 pr = spill[s];
        if (pr.x == m) {
            int vs = pr.y;
            unsigned int p = src32[(size_t)vs * 64 + lane];
            float ex = __expf(fmaxf(el_src[vs * 2 + h] + er, 0.f));
            den += ex;
            acc0 += ex * bflo(p);
            acc1 += ex * bfhi(p);
        }
    }
    float inv = (den > 0.f) ? 1.f / den : 0.f;
    acc0 *= inv; acc1 *= inv;
    float b0 = __shfl_down(acc0, 32);
    float b1 = __shfl_down(acc1, 32);
    if (lane < 32) {
        int e0 = 2 * lane, e1 = 2 * lane + 1;
        float o0 = 0.5f * (acc0 + b0 + bias[e0] + bias[64 + e0]);
        float o1 = 0.5f * (acc1 + b1 + bias[e1] + bias[64 + e1]);
        reinterpret_cast<float2*>(out + (size_t)m * 64)[lane] = make_float2(o0, o1);
    }
}

extern "C" void kernel_launch(void* const* d_in, const int* in_sizes, int n_in,
                              void* d_out, int out_size, void* d_ws, size_t ws_size,
                              hipStream_t stream) {
    const float* vfeat   = (const float*)d_in[0];
    const float* efeat   = (const float*)d_in[1];
    const int*   inc_n   = (const int*)d_in[2];
    const int*   inc_h   = (const int*)d_in[3];
    const float* W_ke    = (const float*)d_in[4];
    const float* W_qe    = (const float*)d_in[5];
    const float* attn_ke = (const float*)d_in[6];
    const float* attn_qe = (const float*)d_in[7];
    const float* bias_e  = (const float*)d_in[8];
    const float* W_kv    = (const float*)d_in[9];
    const float* W_qv    = (const float*)d_in[10];
    const float* attn_kv = (const float*)d_in[11];
    const float* attn_qv = (const float*)d_in[12];
    const float* bias_v  = (const float*)d_in[13];

    float* ws = (float*)d_ws;
    unsigned int*   vke = (unsigned int*)(ws + OFF_VKE);
    unsigned int*   ekv = (unsigned int*)(ws + OFF_EKV);
    float* el   = ws + OFF_EL;
    float* er   = ws + OFF_ER;
    float* el2  = ws + OFF_EL2;
    float* er2  = ws + OFF_ER2;
    float* cqe  = ws + OFF_CQE;
    float* cqv  = ws + OFF_CQV;
    unsigned short* Wt = (unsigned short*)(ws + OFF_WT);
    int*   ib      = (int*)(ws + OFF_INT);
    int*   cur     = ib + I_CUR;
    int*   spc_h   = ib + I_SPCH;
    int*   spc_n   = ib + I_SPCN;
    unsigned short* csrH = (unsigned short*)(ib + I_CSRH);
    unsigned short* csrN = (unsigned short*)(ib + I_CSRN);
    int2*  spill_h = (int2*)(ib + I_SPH);
    int2*  spill_n = (int2*)(ib + I_SPN);

    float* out_v = (float*)d_out;                   // [50000, 64]
    float* out_e = (float*)d_out + (size_t)NN * 64; // [10000, 64]

    // ---- prep: zero cursors + attn folds + W transpose ----
    prep_kernel<<<dim3(66), dim3(256), 0, stream>>>(W_qe, attn_qe, cqe, W_qv, attn_qv, cqv,
                                                    W_ke, Wt, cur);

    // ---- phase1 merged: binning || MFMA GEMM || er rows ----
    phase1_kernel<<<dim3(P1_GRID), dim3(256), 0, stream>>>(
        inc_n, inc_h, cur, csrH, csrN, spc_h, spill_h, spc_n, spill_n,
        vfeat, Wt, attn_ke, cqv, (unsigned short*)vke, el, er2,
        efeat, cqe, er);

    // ---- Phase 1 gather: nodes -> hyperedges ----
    gather_kernel<CAPH><<<dim3((NM + 3) / 4), dim3(256), 0, stream>>>(
        cur, csrH, vke, el, er, bias_e, spc_h, spill_h, out_e, NM);

    // ---- Phase 2: hyperedges -> nodes ----
    gemm64_el_kernel<4><<<dim3((NM + 3) / 4), dim3(128), 0, stream>>>(
        out_e, W_kv, attn_kv, (unsigned short*)ekv, el2, NM);
    gather_kernel<CAPN><<<dim3((NN + 3) / 4), dim3(256), 0, stream>>>(
        cur + NM, csrN, ekv, el2, er2, bias_v, spc_n, spill_n, out_v, NN);
}